// Round 1
// baseline (538.969 us; speedup 1.0000x reference)
//
#include <hip/hip_runtime.h>
#include <hip/hip_bf16.h>

// Pipeline:
//   B=4, C=512, IC=128, N=T*H*W=3136
//   1) conv_in : Th[b,ic,n] = w_theta@maps,  G[b,ic,n] = w_glob@maps   (fp32; bias cancels in BN)
//   2) stats_k : per-channel mean / rsqrt(var+eps) over (b,n)  (12544 samples)
//   3) norm_t  : Thb[b][n][ic] = BN(Th) as bf16 (transposed for Q/K MFMA frags)
//      norm_g  : Gb [b][ic][n] = BN(G)  as bf16 (natural layout for V MFMA frags)
//   4) attn_k  : flash-style  P = exp(QK^T/N) (no max-sub; scores ~ +-0.05),
//                O = P@V / rowsum(P)  via mfma_f32_16x16x32_bf16 -> Yb[b][ic][n] bf16
//   5) conv_out: out = w_up@y + b_up + maps  (fp32)

typedef __attribute__((ext_vector_type(8))) short bf16x8; // 8 bf16 in 4 VGPRs
typedef __attribute__((ext_vector_type(4))) float f32x4;
typedef __attribute__((ext_vector_type(4))) short s16x4;

#define NTOK 3136
#define NELEM 1605632   // 4*128*3136

__device__ inline float bf2f(short u) {
    union { unsigned int i; float f; } v;
    v.i = ((unsigned int)(unsigned short)u) << 16;
    return v.f;
}
__device__ inline short f2bf(float x) {
    union { float f; unsigned int i; } v;
    v.f = x;
    unsigned int r = v.i + 0x7FFFu + ((v.i >> 16) & 1u); // RNE
    return (short)(r >> 16);
}

// ---------------- stage 1: input convs (theta & glob), fp32 -------------
// grid (49, B=4, 8 ic-groups of 16), block 64 (1 wave). lane = n within 64-tile.
__global__ __launch_bounds__(64) void conv_in(const float* __restrict__ maps,
                                              const float* __restrict__ wt,
                                              const float* __restrict__ wg,
                                              float* __restrict__ Th,
                                              float* __restrict__ G)
{
    const int nt = blockIdx.x, b = blockIdx.y, icg = blockIdx.z;
    const int lane = threadIdx.x;
    const int n = nt * 64 + lane;
    const float* mp = maps + (size_t)b * 512 * NTOK + n;
    float acc_t[16], acc_g[16];
#pragma unroll
    for (int k = 0; k < 16; k++) { acc_t[k] = 0.f; acc_g[k] = 0.f; }
    const int icb = icg * 16;
    for (int c = 0; c < 512; c += 8) {
        float m[8];
#pragma unroll
        for (int j = 0; j < 8; j++) m[j] = mp[(size_t)(c + j) * NTOK];
#pragma unroll
        for (int k = 0; k < 16; k++) {
            const float* wtr = wt + (size_t)(icb + k) * 512 + c; // uniform -> s_load
            const float* wgr = wg + (size_t)(icb + k) * 512 + c;
#pragma unroll
            for (int j = 0; j < 8; j++) {
                acc_t[k] = fmaf(wtr[j], m[j], acc_t[k]);
                acc_g[k] = fmaf(wgr[j], m[j], acc_g[k]);
            }
        }
    }
#pragma unroll
    for (int k = 0; k < 16; k++) {
        const size_t o = ((size_t)b * 128 + icb + k) * NTOK + n;
        Th[o] = acc_t[k];
        G[o]  = acc_g[k];
    }
}

// ---------------- stage 2: per-channel stats ----------------------------
// grid 256 (ch: 0-127 theta, 128-255 glob), block 256.
__global__ __launch_bounds__(256) void stats_k(const float* __restrict__ Th,
                                               const float* __restrict__ G,
                                               float* __restrict__ st)
{
    const int ch = blockIdx.x;
    const float* src = (ch < 128) ? Th : G;
    const int ic = ch & 127;
    const int t = threadIdx.x;
    float s = 0.f, s2 = 0.f;
    for (int b = 0; b < 4; b++) {
        const float* p = src + ((size_t)b * 128 + ic) * NTOK;
        for (int n = t; n < NTOK; n += 256) { float x = p[n]; s += x; s2 += x * x; }
    }
#pragma unroll
    for (int off = 32; off; off >>= 1) { s += __shfl_down(s, off); s2 += __shfl_down(s2, off); }
    __shared__ float ls[2][4];
    const int w = t >> 6;
    if ((t & 63) == 0) { ls[0][w] = s; ls[1][w] = s2; }
    __syncthreads();
    if (t == 0) {
        float S = 0.f, S2 = 0.f;
#pragma unroll
        for (int i = 0; i < 4; i++) { S += ls[0][i]; S2 += ls[1][i]; }
        const float mean = S / 12544.f;
        const float var = S2 / 12544.f - mean * mean;
        st[ch] = mean;
        st[256 + ch] = rsqrtf(var + 1e-5f);
    }
}

// ---------------- stage 3a: BN(theta) + transpose -> bf16 [b][n][ic] ----
// grid (49, 4), block 256.
__global__ __launch_bounds__(256) void norm_t(const float* __restrict__ Th,
                                              const float* __restrict__ st,
                                              short* __restrict__ Tb)
{
    __shared__ short tile[64][130]; // +2 pad -> 2-way banks only
    const int b = blockIdx.y, nt = blockIdx.x;
    const int t = threadIdx.x;
    const int nl = t & 63, ics = t >> 6;
    for (int ic = ics; ic < 128; ic += 4) {
        const float mean = st[ic], rstd = st[256 + ic];
        const float x = Th[((size_t)b * 128 + ic) * NTOK + nt * 64 + nl];
        tile[nl][ic] = f2bf((x - mean) * rstd);
    }
    __syncthreads();
    const int ic = t & 127, ns = t >> 7;
    for (int nl2 = ns; nl2 < 64; nl2 += 2) {
        Tb[((size_t)b * NTOK + nt * 64 + nl2) * 128 + ic] = tile[nl2][ic];
    }
}

// ---------------- stage 3b: BN(glob) elementwise -> bf16 [b][ic][n] -----
// grid 6272, block 256 (exact cover of 1,605,632 elements).
__global__ __launch_bounds__(256) void norm_g(const float* __restrict__ G,
                                              const float* __restrict__ st,
                                              short* __restrict__ Gb)
{
    const size_t i = (size_t)blockIdx.x * 256 + threadIdx.x;
    const int ic = (int)((i / NTOK) & 127);
    const float mean = st[128 + ic], rstd = st[256 + 128 + ic];
    Gb[i] = f2bf((G[i] - mean) * rstd);
}

// ---------------- stage 4: attention ------------------------------------
// grid (49, 4), block 256 = 4 waves; wave handles 16 q-rows.
__global__ __launch_bounds__(256) void attn_k(const short* __restrict__ Tb,
                                              const short* __restrict__ Gb,
                                              short* __restrict__ Yb)
{
    constexpr int N = NTOK;
    const int b = blockIdx.y;
    const int wave = __builtin_amdgcn_readfirstlane(threadIdx.x >> 6);
    const int lane = threadIdx.x & 63;
    const int l15 = lane & 15, lhi = lane >> 4;
    const int q0 = blockIdx.x * 64 + wave * 16;
    __shared__ __align__(16) short Pl[4][16][40]; // per-wave 16x32 P tile, stride 40 bf16
    short (*P)[40] = Pl[wave];
    const short* tb = Tb + (size_t)b * N * 128;
    const short* gb = Gb + (size_t)b * 128 * N;

    bf16x8 qf[4];
#pragma unroll
    for (int ks = 0; ks < 4; ks++)
        qf[ks] = *(const bf16x8*)(tb + (size_t)(q0 + l15) * 128 + ks * 32 + lhi * 8);

    f32x4 acc[8];
#pragma unroll
    for (int i = 0; i < 8; i++) acc[i] = f32x4{0.f, 0.f, 0.f, 0.f};
    float denom[4] = {0.f, 0.f, 0.f, 0.f};
    const float inv_n = 1.0f / (float)N;

    for (int m0 = 0; m0 < N; m0 += 32) {
        f32x4 s0 = f32x4{0.f, 0.f, 0.f, 0.f};
        f32x4 s1 = f32x4{0.f, 0.f, 0.f, 0.f};
#pragma unroll
        for (int ks = 0; ks < 4; ks++) {
            bf16x8 kf0 = *(const bf16x8*)(tb + (size_t)(m0 + l15) * 128 + ks * 32 + lhi * 8);
            bf16x8 kf1 = *(const bf16x8*)(tb + (size_t)(m0 + 16 + l15) * 128 + ks * 32 + lhi * 8);
            s0 = __builtin_amdgcn_mfma_f32_16x16x32_bf16(qf[ks], kf0, s0, 0, 0, 0);
            s1 = __builtin_amdgcn_mfma_f32_16x16x32_bf16(qf[ks], kf1, s1, 0, 0, 0);
        }
        // C/D layout (HW-verified): col = lane&15 (=m), row = (lane>>4)*4 + r (=q_local)
#pragma unroll
        for (int r = 0; r < 4; r++) {
            const float p0 = __expf(s0[r] * inv_n);
            const float p1 = __expf(s1[r] * inv_n);
            denom[r] += p0 + p1;
            P[lhi * 4 + r][l15]      = f2bf(p0);
            P[lhi * 4 + r][16 + l15] = f2bf(p1);
        }
        // PV: A-frag = P[row=l15][k=lhi*8..+8] (compiler inserts lgkmcnt wait; wave-local)
        bf16x8 pa = *(const bf16x8*)(&P[l15][lhi * 8]);
#pragma unroll
        for (int it = 0; it < 8; it++) {
            bf16x8 vf = *(const bf16x8*)(gb + (size_t)(it * 16 + l15) * N + m0 + lhi * 8);
            acc[it] = __builtin_amdgcn_mfma_f32_16x16x32_bf16(pa, vf, acc[it], 0, 0, 0);
        }
    }
    // reduce denom over the 16 lanes (m-spread) sharing each q-row group
#pragma unroll
    for (int off = 1; off < 16; off <<= 1) {
#pragma unroll
        for (int r = 0; r < 4; r++) denom[r] += __shfl_xor(denom[r], off);
    }
    float rd[4];
#pragma unroll
    for (int r = 0; r < 4; r++) rd[r] = 1.0f / denom[r];
#pragma unroll
    for (int it = 0; it < 8; it++) {
        s16x4 v;
#pragma unroll
        for (int r = 0; r < 4; r++) v[r] = f2bf(acc[it][r] * rd[r]);
        *(s16x4*)(Yb + (size_t)b * 128 * N + (size_t)(it * 16 + l15) * N + q0 + lhi * 4) = v;
    }
}

// ---------------- stage 5: up conv + bias + residual --------------------
// grid (49, 4 c-groups, B=4), block 256; wave w covers 32 out channels.
__global__ __launch_bounds__(256) void conv_out(const short* __restrict__ Yb,
                                                const float* __restrict__ wup,
                                                const float* __restrict__ bup,
                                                const float* __restrict__ maps,
                                                float* __restrict__ out)
{
    const int nt = blockIdx.x, cg = blockIdx.y, b = blockIdx.z;
    const int lane = threadIdx.x & 63;
    const int w = __builtin_amdgcn_readfirstlane(threadIdx.x >> 6);
    const int n = nt * 64 + lane;
    const int cb = cg * 128 + w * 32;
    const short* yb = Yb + (size_t)b * 128 * NTOK + n;
    float acc[32];
#pragma unroll
    for (int k = 0; k < 32; k++) acc[k] = bup[cb + k];
    for (int ic = 0; ic < 128; ic += 8) {
        float y[8];
#pragma unroll
        for (int j = 0; j < 8; j++) y[j] = bf2f(yb[(size_t)(ic + j) * NTOK]);
#pragma unroll
        for (int k = 0; k < 32; k++) {
            const float* wr = wup + (size_t)(cb + k) * 128 + ic; // uniform -> s_load
#pragma unroll
            for (int j = 0; j < 8; j++) acc[k] = fmaf(wr[j], y[j], acc[k]);
        }
    }
#pragma unroll
    for (int k = 0; k < 32; k++) {
        const size_t o = ((size_t)b * 512 + cb + k) * NTOK + n;
        out[o] = acc[k] + maps[o];
    }
}

extern "C" void kernel_launch(void* const* d_in, const int* in_sizes, int n_in,
                              void* d_out, int out_size, void* d_ws, size_t ws_size,
                              hipStream_t stream)
{
    const float* maps    = (const float*)d_in[0];
    const float* w_theta = (const float*)d_in[1];
    // d_in[2] b_theta, d_in[3] w_phalt, d_in[4] b_phalt: unused (BN cancels bias; phalt dead)
    const float* w_glob  = (const float*)d_in[5];
    // d_in[6] b_glob unused
    const float* w_up    = (const float*)d_in[7];
    const float* b_up    = (const float*)d_in[8];
    float* out = (float*)d_out;

    float* Th = (float*)d_ws;            // 1,605,632 f32
    float* G  = Th + NELEM;              // 1,605,632 f32
    float* st = G + NELEM;               // 512 f32 (mean[256], rstd[256])
    short* Tb = (short*)(st + 512);      // bf16 [b][n][ic]
    short* Gb = Tb + NELEM;              // bf16 [b][ic][n]
    short* Yb = Gb + NELEM;              // bf16 [b][ic][n]
    // total ws: ~22.5 MB

    conv_in <<<dim3(49, 4, 8), 64,  0, stream>>>(maps, w_theta, w_glob, Th, G);
    stats_k <<<256,            256, 0, stream>>>(Th, G, st);
    norm_t  <<<dim3(49, 4),    256, 0, stream>>>(Th, st, Tb);
    norm_g  <<<6272,           256, 0, stream>>>(G, st, Gb);
    attn_k  <<<dim3(49, 4),    256, 0, stream>>>(Tb, Gb, Yb);
    conv_out<<<dim3(49, 4, 4), 256, 0, stream>>>(Yb, w_up, b_up, maps, out);
}

// Round 2
// 260.632 us; speedup vs baseline: 2.0679x; 2.0679x over previous
//
#include <hip/hip_runtime.h>
#include <hip/hip_bf16.h>

// B=4, C=512, IC=128, N=3136
// prep_w     : bf16-ize weights  Wb[256][512] (theta|glob stacked), wupb[512][128]
// transT     : maps f32 [b][c][n] -> mapsT bf16 [b][n][c]   (LDS transpose)
// conv_in_m  : MFMA GEMM -> Tpre/Gpre bf16 [b][ic][n]  (pre-norm; bias cancels in BN)
// stats_k    : per-channel mean / rsqrt(var+eps) over (b,n)
// norm_t     : BN(Tpre) -> Tb bf16 [b][n][ic] (transposed for Q/K frags)
// norm_g     : BN(Gpre) -> Gb bf16 [b][ic][n]
// attn_k     : flash-style softmax(QK^T/N)@V via mfma 16x16x32 -> Yt bf16 [b][n][ic]
// conv_out_m : MFMA GEMM out = w_up@y + b_up + maps (fp32)

typedef __attribute__((ext_vector_type(8))) short bf16x8;
typedef __attribute__((ext_vector_type(4))) float f32x4;
typedef __attribute__((ext_vector_type(4))) short s16x4;

#define NTOK 3136
#define NELEM 1605632   // 4*128*3136

__device__ inline float bf2f(short u) {
    union { unsigned int i; float f; } v;
    v.i = ((unsigned int)(unsigned short)u) << 16;
    return v.f;
}
__device__ inline short f2bf(float x) {
    union { float f; unsigned int i; } v;
    v.f = x;
    unsigned int r = v.i + 0x7FFFu + ((v.i >> 16) & 1u); // RNE
    return (short)(r >> 16);
}

// ---------------- prep: weights -> bf16 ---------------------------------
// grid 768, block 256: 131072 (Wb) + 65536 (wupb) elements, exact cover.
__global__ __launch_bounds__(256) void prep_w(const float* __restrict__ wt,
                                              const float* __restrict__ wg,
                                              const float* __restrict__ wup,
                                              short* __restrict__ Wb,
                                              short* __restrict__ wupb)
{
    const int i = blockIdx.x * 256 + threadIdx.x;
    if (i < 131072) {
        const int r = i >> 9;           // 0..255
        const int c = i & 511;
        const float w = (r < 128) ? wt[(size_t)r * 512 + c] : wg[(size_t)(r - 128) * 512 + c];
        Wb[i] = f2bf(w);
    } else {
        const int j = i - 131072;       // 0..65535
        wupb[j] = f2bf(wup[j]);
    }
}

// ---------------- transpose maps -> bf16 [b][n][c] ----------------------
// grid (49, 8, 4), block 256. Tile 64c x 64n via LDS.
__global__ __launch_bounds__(256) void transT(const float* __restrict__ maps,
                                              short* __restrict__ mapsT)
{
    __shared__ short tile[64][66]; // stride 66 shorts = 33 dwords -> conflict-free col reads
    const int nt = blockIdx.x, cg = blockIdx.y, b = blockIdx.z;
    const int n0 = nt * 64, c0 = cg * 64;
    const int t = threadIdx.x;
    const int nl = t & 63, cq = t >> 6;
#pragma unroll
    for (int i = 0; i < 16; i++) {
        const int cl = i * 4 + cq;
        tile[cl][nl] = f2bf(maps[((size_t)b * 512 + c0 + cl) * NTOK + n0 + nl]);
    }
    __syncthreads();
    const int cl2 = t & 63, nq = t >> 6;
#pragma unroll
    for (int i = 0; i < 16; i++) {
        const int nl2 = i * 4 + nq;
        mapsT[((size_t)b * NTOK + n0 + nl2) * 512 + c0 + cl2] = tile[cl2][nl2];
    }
}

// ---------------- conv_in via MFMA --------------------------------------
// grid (49, 4, 2:theta/glob), block 256 = 4 waves; wave w -> 32 ic rows.
// A = Wb rows (z*128..), B = mapsT[b] rows (n-major, k contiguous).
__global__ __launch_bounds__(256) void conv_in_m(const short* __restrict__ Wb,
                                                 const short* __restrict__ mapsT,
                                                 short* __restrict__ Tpre,
                                                 short* __restrict__ Gpre)
{
    const int n0 = blockIdx.x * 64, b = blockIdx.y, z = blockIdx.z;
    const int wv = __builtin_amdgcn_readfirstlane(threadIdx.x >> 6);
    const int lane = threadIdx.x & 63;
    const int l15 = lane & 15, lhi = lane >> 4;
    const short* A = Wb + (size_t)z * 128 * 512;
    const short* Bp = mapsT + (size_t)b * NTOK * 512;
    short* out = (z ? Gpre : Tpre) + (size_t)b * 128 * NTOK;
    const int ic0 = wv * 32;

    f32x4 acc[2][4];
#pragma unroll
    for (int g = 0; g < 2; g++)
#pragma unroll
        for (int j = 0; j < 4; j++) acc[g][j] = f32x4{0.f, 0.f, 0.f, 0.f};

    for (int ks = 0; ks < 16; ks++) {
        const int k0 = ks * 32 + lhi * 8;
        bf16x8 af[2], bf[4];
#pragma unroll
        for (int g = 0; g < 2; g++)
            af[g] = *(const bf16x8*)(A + (size_t)(ic0 + g * 16 + l15) * 512 + k0);
#pragma unroll
        for (int j = 0; j < 4; j++)
            bf[j] = *(const bf16x8*)(Bp + (size_t)(n0 + j * 16 + l15) * 512 + k0);
#pragma unroll
        for (int g = 0; g < 2; g++)
#pragma unroll
            for (int j = 0; j < 4; j++)
                acc[g][j] = __builtin_amdgcn_mfma_f32_16x16x32_bf16(af[g], bf[j], acc[g][j], 0, 0, 0);
    }
    // D layout: col(l15) = n (B row), row(lhi*4+r) = ic (A row)
#pragma unroll
    for (int g = 0; g < 2; g++)
#pragma unroll
        for (int j = 0; j < 4; j++)
#pragma unroll
            for (int r = 0; r < 4; r++) {
                const int ic = ic0 + g * 16 + lhi * 4 + r;
                const int n = n0 + j * 16 + l15;
                out[(size_t)ic * NTOK + n] = f2bf(acc[g][j][r]);
            }
}

// ---------------- stats: per-channel mean/rstd over (b,n) ---------------
// grid 256 (0-127 theta, 128-255 glob), block 256.
__global__ __launch_bounds__(256) void stats_k(const short* __restrict__ Tpre,
                                               const short* __restrict__ Gpre,
                                               float* __restrict__ st)
{
    const int ch = blockIdx.x;
    const short* src = (ch < 128) ? Tpre : Gpre;
    const int ic = ch & 127;
    const int t = threadIdx.x;
    float s = 0.f, s2 = 0.f;
    for (int b = 0; b < 4; b++) {
        const short* p = src + ((size_t)b * 128 + ic) * NTOK;
        for (int n8 = t; n8 < 392; n8 += 256) {
            bf16x8 v = *(const bf16x8*)(p + n8 * 8);
#pragma unroll
            for (int j = 0; j < 8; j++) { float x = bf2f(v[j]); s += x; s2 += x * x; }
        }
    }
#pragma unroll
    for (int off = 32; off; off >>= 1) { s += __shfl_down(s, off); s2 += __shfl_down(s2, off); }
    __shared__ float ls[2][4];
    const int w = t >> 6;
    if ((t & 63) == 0) { ls[0][w] = s; ls[1][w] = s2; }
    __syncthreads();
    if (t == 0) {
        float S = 0.f, S2 = 0.f;
#pragma unroll
        for (int i = 0; i < 4; i++) { S += ls[0][i]; S2 += ls[1][i]; }
        const float mean = S / 12544.f;
        const float var = S2 / 12544.f - mean * mean;
        st[ch] = mean;
        st[256 + ch] = rsqrtf(var + 1e-5f);
    }
}

// ---------------- BN(theta) + transpose -> Tb [b][n][ic] ----------------
__global__ __launch_bounds__(256) void norm_t(const short* __restrict__ Tpre,
                                              const float* __restrict__ st,
                                              short* __restrict__ Tb)
{
    __shared__ short tile[64][130];
    const int b = blockIdx.y, nt = blockIdx.x;
    const int t = threadIdx.x;
    const int nl = t & 63, ics = t >> 6;
    for (int ic = ics; ic < 128; ic += 4) {
        const float mean = st[ic], rstd = st[256 + ic];
        const float x = bf2f(Tpre[((size_t)b * 128 + ic) * NTOK + nt * 64 + nl]);
        tile[nl][ic] = f2bf((x - mean) * rstd);
    }
    __syncthreads();
    const int ic = t & 127, ns = t >> 7;
    for (int nl2 = ns; nl2 < 64; nl2 += 2) {
        Tb[((size_t)b * NTOK + nt * 64 + nl2) * 128 + ic] = tile[nl2][ic];
    }
}

// ---------------- BN(glob) elementwise -> Gb [b][ic][n] -----------------
// grid 784, block 256, 8 elems/thread (within one channel: 3136 % 8 == 0).
__global__ __launch_bounds__(256) void norm_g(const short* __restrict__ Gpre,
                                              const float* __restrict__ st,
                                              short* __restrict__ Gb)
{
    const size_t base = ((size_t)blockIdx.x * 256 + threadIdx.x) * 8;
    const int ic = (int)((base / NTOK) & 127);
    const float mean = st[128 + ic], rstd = st[256 + 128 + ic];
    bf16x8 v = *(const bf16x8*)(Gpre + base);
    bf16x8 o;
#pragma unroll
    for (int j = 0; j < 8; j++) o[j] = f2bf((bf2f(v[j]) - mean) * rstd);
    *(bf16x8*)(Gb + base) = o;
}

// ---------------- attention ---------------------------------------------
// grid (49, 4), block 256 = 4 waves; wave handles 16 q-rows. Output Yt [b][n][ic].
__global__ __launch_bounds__(256) void attn_k(const short* __restrict__ Tb,
                                              const short* __restrict__ Gb,
                                              short* __restrict__ Yt)
{
    constexpr int N = NTOK;
    const int b = blockIdx.y;
    const int wave = __builtin_amdgcn_readfirstlane(threadIdx.x >> 6);
    const int lane = threadIdx.x & 63;
    const int l15 = lane & 15, lhi = lane >> 4;
    const int q0 = blockIdx.x * 64 + wave * 16;
    __shared__ __align__(16) short Pl[4][16][40];
    short (*P)[40] = Pl[wave];
    const short* tb = Tb + (size_t)b * N * 128;
    const short* gb = Gb + (size_t)b * 128 * N;

    bf16x8 qf[4];
#pragma unroll
    for (int ks = 0; ks < 4; ks++)
        qf[ks] = *(const bf16x8*)(tb + (size_t)(q0 + l15) * 128 + ks * 32 + lhi * 8);

    f32x4 acc[8];
#pragma unroll
    for (int i = 0; i < 8; i++) acc[i] = f32x4{0.f, 0.f, 0.f, 0.f};
    float denom[4] = {0.f, 0.f, 0.f, 0.f};
    const float inv_n = 1.0f / (float)N;

    for (int m0 = 0; m0 < N; m0 += 32) {
        f32x4 s0 = f32x4{0.f, 0.f, 0.f, 0.f};
        f32x4 s1 = f32x4{0.f, 0.f, 0.f, 0.f};
#pragma unroll
        for (int ks = 0; ks < 4; ks++) {
            bf16x8 kf0 = *(const bf16x8*)(tb + (size_t)(m0 + l15) * 128 + ks * 32 + lhi * 8);
            bf16x8 kf1 = *(const bf16x8*)(tb + (size_t)(m0 + 16 + l15) * 128 + ks * 32 + lhi * 8);
            s0 = __builtin_amdgcn_mfma_f32_16x16x32_bf16(qf[ks], kf0, s0, 0, 0, 0);
            s1 = __builtin_amdgcn_mfma_f32_16x16x32_bf16(qf[ks], kf1, s1, 0, 0, 0);
        }
#pragma unroll
        for (int r = 0; r < 4; r++) {
            const float p0 = __expf(s0[r] * inv_n);
            const float p1 = __expf(s1[r] * inv_n);
            denom[r] += p0 + p1;
            P[lhi * 4 + r][l15]      = f2bf(p0);
            P[lhi * 4 + r][16 + l15] = f2bf(p1);
        }
        bf16x8 pa = *(const bf16x8*)(&P[l15][lhi * 8]);
#pragma unroll
        for (int it = 0; it < 8; it++) {
            bf16x8 vf = *(const bf16x8*)(gb + (size_t)(it * 16 + l15) * N + m0 + lhi * 8);
            acc[it] = __builtin_amdgcn_mfma_f32_16x16x32_bf16(pa, vf, acc[it], 0, 0, 0);
        }
    }
#pragma unroll
    for (int off = 1; off < 16; off <<= 1) {
#pragma unroll
        for (int r = 0; r < 4; r++) denom[r] += __shfl_xor(denom[r], off);
    }
    float rd[4];
#pragma unroll
    for (int r = 0; r < 4; r++) rd[r] = 1.0f / denom[r];
    // acc layout: ic = it*16 + l15 (B row), n = q0 + lhi*4 + r (A row)
#pragma unroll
    for (int it = 0; it < 8; it++) {
#pragma unroll
        for (int r = 0; r < 4; r++) {
            const int n = q0 + lhi * 4 + r;
            Yt[((size_t)b * N + n) * 128 + it * 16 + l15] = f2bf(acc[it][r] * rd[r]);
        }
    }
}

// ---------------- conv_out via MFMA + bias + residual -------------------
// grid (98, 4), block 256 = 4 waves; wave -> 128 out-channels, block n-tile 32.
__global__ __launch_bounds__(256) void conv_out_m(const short* __restrict__ Yt,
                                                  const short* __restrict__ wupb,
                                                  const float* __restrict__ bup,
                                                  const float* __restrict__ maps,
                                                  float* __restrict__ out)
{
    const int n0 = blockIdx.x * 32, b = blockIdx.y;
    const int wv = __builtin_amdgcn_readfirstlane(threadIdx.x >> 6);
    const int lane = threadIdx.x & 63;
    const int l15 = lane & 15, lhi = lane >> 4;
    const int c0 = wv * 128;
    const short* yp = Yt + (size_t)b * NTOK * 128;

    f32x4 acc[8][2];
#pragma unroll
    for (int g = 0; g < 8; g++)
#pragma unroll
        for (int j = 0; j < 2; j++) acc[g][j] = f32x4{0.f, 0.f, 0.f, 0.f};

#pragma unroll
    for (int ks = 0; ks < 4; ks++) {
        const int k0 = ks * 32 + lhi * 8;
        bf16x8 af[8], bf[2];
#pragma unroll
        for (int g = 0; g < 8; g++)
            af[g] = *(const bf16x8*)(wupb + (size_t)(c0 + g * 16 + l15) * 128 + k0);
#pragma unroll
        for (int j = 0; j < 2; j++)
            bf[j] = *(const bf16x8*)(yp + (size_t)(n0 + j * 16 + l15) * 128 + k0);
#pragma unroll
        for (int g = 0; g < 8; g++)
#pragma unroll
            for (int j = 0; j < 2; j++)
                acc[g][j] = __builtin_amdgcn_mfma_f32_16x16x32_bf16(af[g], bf[j], acc[g][j], 0, 0, 0);
    }
#pragma unroll
    for (int g = 0; g < 8; g++)
#pragma unroll
        for (int j = 0; j < 2; j++)
#pragma unroll
            for (int r = 0; r < 4; r++) {
                const int c = c0 + g * 16 + lhi * 4 + r;
                const int n = n0 + j * 16 + l15;
                const size_t o = ((size_t)b * 512 + c) * NTOK + n;
                out[o] = acc[g][j][r] + bup[c] + maps[o];
            }
}

extern "C" void kernel_launch(void* const* d_in, const int* in_sizes, int n_in,
                              void* d_out, int out_size, void* d_ws, size_t ws_size,
                              hipStream_t stream)
{
    const float* maps    = (const float*)d_in[0];
    const float* w_theta = (const float*)d_in[1];
    const float* w_glob  = (const float*)d_in[5];
    const float* w_up    = (const float*)d_in[7];
    const float* b_up    = (const float*)d_in[8];
    float* out = (float*)d_out;

    // workspace (~19.7 MB): Tb/Gb/Yt overlay the dead mapsT region (stream-ordered)
    short* mapsT = (short*)d_ws;               // 4*3136*512 = 6,422,528 shorts
    short* Tb    = mapsT;                      // NELEM shorts (overlay)
    short* Gb    = mapsT + NELEM;              // NELEM shorts (overlay)
    short* Yt    = mapsT + 2 * (size_t)NELEM;  // NELEM shorts (overlay; 3*NELEM < 6422528)
    short* Tpre  = mapsT + 6422528;            // NELEM shorts
    short* Gpre  = Tpre + NELEM;               // NELEM shorts
    short* Wb    = Gpre + NELEM;               // 131072 shorts
    short* wupb  = Wb + 131072;                // 65536 shorts
    float* st    = (float*)(wupb + 65536);     // 512 f32

    prep_w    <<<768,            256, 0, stream>>>(w_theta, w_glob, w_up, Wb, wupb);
    transT    <<<dim3(49, 8, 4), 256, 0, stream>>>(maps, mapsT);
    conv_in_m <<<dim3(49, 4, 2), 256, 0, stream>>>(Wb, mapsT, Tpre, Gpre);
    stats_k   <<<256,            256, 0, stream>>>(Tpre, Gpre, st);
    norm_t    <<<dim3(49, 4),    256, 0, stream>>>(Tpre, st, Tb);
    norm_g    <<<784,            256, 0, stream>>>(Gpre, st, Gb);
    attn_k    <<<dim3(49, 4),    256, 0, stream>>>(Tb, Gb, Yt);
    conv_out_m<<<dim3(98, 4),    256, 0, stream>>>(Yt, wupb, b_up, maps, out);
}

// Round 3
// 256.062 us; speedup vs baseline: 2.1048x; 1.0178x over previous
//
#include <hip/hip_runtime.h>
#include <hip/hip_bf16.h>

// B=4, C=512, IC=128, N=3136
// prep_w     : bf16-ize weights  Wb[256][512] (theta|glob stacked), wupb[512][128]
// transT     : maps f32 [b][c][n] -> mapsT bf16 [b][n][c]   (LDS transpose)
// conv_in_m  : MFMA GEMM -> Tpre/Gpre bf16 [b][ic][n]  (pre-norm; bias cancels in BN)
// stats_k    : per-channel mean / rsqrt(var+eps) over (b,n)
// norm_t     : BN(Tpre) -> Tb bf16 [b][n][ic] (transposed for Q/K frags)
// norm_g     : BN(Gpre) -> Gb bf16 [b][ic][n]
// attn_k     : KV-split (S=4) flash attention, unnormalized partials:
//              Opart[s][b][n][ic] (f32, stored in d_out) + dpart[s][b][n]
// combine_k  : Yt[b][n][ic] = (sum_s Opart) / (sum_s dpart)  as bf16
// conv_out_m : MFMA GEMM out = w_up@y + b_up + maps (fp32), overwrites d_out

typedef __attribute__((ext_vector_type(8))) short bf16x8;
typedef __attribute__((ext_vector_type(4))) float f32x4;
typedef __attribute__((ext_vector_type(4))) short s16x4;

#define NTOK 3136
#define NELEM 1605632   // 4*128*3136
#define NSPLIT 4

__device__ inline float bf2f(short u) {
    union { unsigned int i; float f; } v;
    v.i = ((unsigned int)(unsigned short)u) << 16;
    return v.f;
}
__device__ inline short f2bf(float x) {
    union { float f; unsigned int i; } v;
    v.f = x;
    unsigned int r = v.i + 0x7FFFu + ((v.i >> 16) & 1u); // RNE
    return (short)(r >> 16);
}

// ---------------- prep: weights -> bf16 ---------------------------------
__global__ __launch_bounds__(256) void prep_w(const float* __restrict__ wt,
                                              const float* __restrict__ wg,
                                              const float* __restrict__ wup,
                                              short* __restrict__ Wb,
                                              short* __restrict__ wupb)
{
    const int i = blockIdx.x * 256 + threadIdx.x;
    if (i < 131072) {
        const int r = i >> 9;
        const int c = i & 511;
        const float w = (r < 128) ? wt[(size_t)r * 512 + c] : wg[(size_t)(r - 128) * 512 + c];
        Wb[i] = f2bf(w);
    } else {
        const int j = i - 131072;
        wupb[j] = f2bf(wup[j]);
    }
}

// ---------------- transpose maps -> bf16 [b][n][c] ----------------------
__global__ __launch_bounds__(256) void transT(const float* __restrict__ maps,
                                              short* __restrict__ mapsT)
{
    __shared__ short tile[64][66];
    const int nt = blockIdx.x, cg = blockIdx.y, b = blockIdx.z;
    const int n0 = nt * 64, c0 = cg * 64;
    const int t = threadIdx.x;
    const int nl = t & 63, cq = t >> 6;
#pragma unroll
    for (int i = 0; i < 16; i++) {
        const int cl = i * 4 + cq;
        tile[cl][nl] = f2bf(maps[((size_t)b * 512 + c0 + cl) * NTOK + n0 + nl]);
    }
    __syncthreads();
    const int cl2 = t & 63, nq = t >> 6;
#pragma unroll
    for (int i = 0; i < 16; i++) {
        const int nl2 = i * 4 + nq;
        mapsT[((size_t)b * NTOK + n0 + nl2) * 512 + c0 + cl2] = tile[cl2][nl2];
    }
}

// ---------------- conv_in via MFMA --------------------------------------
__global__ __launch_bounds__(256) void conv_in_m(const short* __restrict__ Wb,
                                                 const short* __restrict__ mapsT,
                                                 short* __restrict__ Tpre,
                                                 short* __restrict__ Gpre)
{
    const int n0 = blockIdx.x * 64, b = blockIdx.y, z = blockIdx.z;
    const int wv = __builtin_amdgcn_readfirstlane(threadIdx.x >> 6);
    const int lane = threadIdx.x & 63;
    const int l15 = lane & 15, lhi = lane >> 4;
    const short* A = Wb + (size_t)z * 128 * 512;
    const short* Bp = mapsT + (size_t)b * NTOK * 512;
    short* out = (z ? Gpre : Tpre) + (size_t)b * 128 * NTOK;
    const int ic0 = wv * 32;

    f32x4 acc[2][4];
#pragma unroll
    for (int g = 0; g < 2; g++)
#pragma unroll
        for (int j = 0; j < 4; j++) acc[g][j] = f32x4{0.f, 0.f, 0.f, 0.f};

    for (int ks = 0; ks < 16; ks++) {
        const int k0 = ks * 32 + lhi * 8;
        bf16x8 af[2], bf[4];
#pragma unroll
        for (int g = 0; g < 2; g++)
            af[g] = *(const bf16x8*)(A + (size_t)(ic0 + g * 16 + l15) * 512 + k0);
#pragma unroll
        for (int j = 0; j < 4; j++)
            bf[j] = *(const bf16x8*)(Bp + (size_t)(n0 + j * 16 + l15) * 512 + k0);
#pragma unroll
        for (int g = 0; g < 2; g++)
#pragma unroll
            for (int j = 0; j < 4; j++)
                acc[g][j] = __builtin_amdgcn_mfma_f32_16x16x32_bf16(af[g], bf[j], acc[g][j], 0, 0, 0);
    }
#pragma unroll
    for (int g = 0; g < 2; g++)
#pragma unroll
        for (int j = 0; j < 4; j++)
#pragma unroll
            for (int r = 0; r < 4; r++) {
                const int ic = ic0 + g * 16 + lhi * 4 + r;
                const int n = n0 + j * 16 + l15;
                out[(size_t)ic * NTOK + n] = f2bf(acc[g][j][r]);
            }
}

// ---------------- stats ---------------------------------------------------
__global__ __launch_bounds__(256) void stats_k(const short* __restrict__ Tpre,
                                               const short* __restrict__ Gpre,
                                               float* __restrict__ st)
{
    const int ch = blockIdx.x;
    const short* src = (ch < 128) ? Tpre : Gpre;
    const int ic = ch & 127;
    const int t = threadIdx.x;
    float s = 0.f, s2 = 0.f;
    for (int b = 0; b < 4; b++) {
        const short* p = src + ((size_t)b * 128 + ic) * NTOK;
        for (int n8 = t; n8 < 392; n8 += 256) {
            bf16x8 v = *(const bf16x8*)(p + n8 * 8);
#pragma unroll
            for (int j = 0; j < 8; j++) { float x = bf2f(v[j]); s += x; s2 += x * x; }
        }
    }
#pragma unroll
    for (int off = 32; off; off >>= 1) { s += __shfl_down(s, off); s2 += __shfl_down(s2, off); }
    __shared__ float ls[2][4];
    const int w = t >> 6;
    if ((t & 63) == 0) { ls[0][w] = s; ls[1][w] = s2; }
    __syncthreads();
    if (t == 0) {
        float S = 0.f, S2 = 0.f;
#pragma unroll
        for (int i = 0; i < 4; i++) { S += ls[0][i]; S2 += ls[1][i]; }
        const float mean = S / 12544.f;
        const float var = S2 / 12544.f - mean * mean;
        st[ch] = mean;
        st[256 + ch] = rsqrtf(var + 1e-5f);
    }
}

// ---------------- BN(theta) + transpose -> Tb [b][n][ic] ----------------
__global__ __launch_bounds__(256) void norm_t(const short* __restrict__ Tpre,
                                              const float* __restrict__ st,
                                              short* __restrict__ Tb)
{
    __shared__ short tile[64][130];
    const int b = blockIdx.y, nt = blockIdx.x;
    const int t = threadIdx.x;
    const int nl = t & 63, ics = t >> 6;
    for (int ic = ics; ic < 128; ic += 4) {
        const float mean = st[ic], rstd = st[256 + ic];
        const float x = bf2f(Tpre[((size_t)b * 128 + ic) * NTOK + nt * 64 + nl]);
        tile[nl][ic] = f2bf((x - mean) * rstd);
    }
    __syncthreads();
    const int ic = t & 127, ns = t >> 7;
    for (int nl2 = ns; nl2 < 64; nl2 += 2) {
        Tb[((size_t)b * NTOK + nt * 64 + nl2) * 128 + ic] = tile[nl2][ic];
    }
}

// ---------------- BN(glob) -> Gb [b][ic][n] -----------------------------
__global__ __launch_bounds__(256) void norm_g(const short* __restrict__ Gpre,
                                              const float* __restrict__ st,
                                              short* __restrict__ Gb)
{
    const size_t base = ((size_t)blockIdx.x * 256 + threadIdx.x) * 8;
    const int ic = (int)((base / NTOK) & 127);
    const float mean = st[128 + ic], rstd = st[256 + 128 + ic];
    bf16x8 v = *(const bf16x8*)(Gpre + base);
    bf16x8 o;
#pragma unroll
    for (int j = 0; j < 8; j++) o[j] = f2bf((bf2f(v[j]) - mean) * rstd);
    *(bf16x8*)(Gb + base) = o;
}

// ---------------- attention, KV-split partials --------------------------
// grid (49, B=4, S=4), block 256 = 4 waves (16 q-rows each, shared m-tiles).
// Split s handles m-tiles s, s+4, s+8, ... (of 98). Emits unnormalized
// Opart[s][b][n][ic] f32 (into d_out) and dpart[s][b][n].
__global__ __launch_bounds__(256) void attn_k(const short* __restrict__ Tb,
                                              const short* __restrict__ Gb,
                                              float* __restrict__ Opart,
                                              float* __restrict__ dpart)
{
    constexpr int N = NTOK;
    const int b = blockIdx.y, s = blockIdx.z;
    const int wave = __builtin_amdgcn_readfirstlane(threadIdx.x >> 6);
    const int lane = threadIdx.x & 63;
    const int l15 = lane & 15, lhi = lane >> 4;
    const int q0 = blockIdx.x * 64 + wave * 16;
    __shared__ __align__(16) short Pl[4][16][40];
    short (*P)[40] = Pl[wave];
    const short* tb = Tb + (size_t)b * N * 128;
    const short* gb = Gb + (size_t)b * 128 * N;

    bf16x8 qf[4];
#pragma unroll
    for (int ks = 0; ks < 4; ks++)
        qf[ks] = *(const bf16x8*)(tb + (size_t)(q0 + l15) * 128 + ks * 32 + lhi * 8);

    f32x4 acc[8];
#pragma unroll
    for (int i = 0; i < 8; i++) acc[i] = f32x4{0.f, 0.f, 0.f, 0.f};
    float denom[4] = {0.f, 0.f, 0.f, 0.f};
    const float inv_n = 1.0f / (float)N;

    for (int mt = s; mt < 98; mt += NSPLIT) {
        const int m0 = mt * 32;
        f32x4 s0 = f32x4{0.f, 0.f, 0.f, 0.f};
        f32x4 s1 = f32x4{0.f, 0.f, 0.f, 0.f};
#pragma unroll
        for (int ks = 0; ks < 4; ks++) {
            bf16x8 kf0 = *(const bf16x8*)(tb + (size_t)(m0 + l15) * 128 + ks * 32 + lhi * 8);
            bf16x8 kf1 = *(const bf16x8*)(tb + (size_t)(m0 + 16 + l15) * 128 + ks * 32 + lhi * 8);
            s0 = __builtin_amdgcn_mfma_f32_16x16x32_bf16(qf[ks], kf0, s0, 0, 0, 0);
            s1 = __builtin_amdgcn_mfma_f32_16x16x32_bf16(qf[ks], kf1, s1, 0, 0, 0);
        }
        // D layout: col = l15 (=m), row = lhi*4 + r (=q_local)
#pragma unroll
        for (int r = 0; r < 4; r++) {
            const float p0 = __expf(s0[r] * inv_n);
            const float p1 = __expf(s1[r] * inv_n);
            denom[r] += p0 + p1;
            P[lhi * 4 + r][l15]      = f2bf(p0);
            P[lhi * 4 + r][16 + l15] = f2bf(p1);
        }
        bf16x8 pa = *(const bf16x8*)(&P[l15][lhi * 8]);
#pragma unroll
        for (int it = 0; it < 8; it++) {
            bf16x8 vf = *(const bf16x8*)(gb + (size_t)(it * 16 + l15) * N + m0 + lhi * 8);
            acc[it] = __builtin_amdgcn_mfma_f32_16x16x32_bf16(pa, vf, acc[it], 0, 0, 0);
        }
    }
    // reduce denom across the 16 m-lanes of each q-row group
#pragma unroll
    for (int off = 1; off < 16; off <<= 1) {
#pragma unroll
        for (int r = 0; r < 4; r++) denom[r] += __shfl_xor(denom[r], off);
    }
    float* op = Opart + ((size_t)(s * 4 + b)) * N * 128;
    // acc layout: ic = it*16 + l15, n = q0 + lhi*4 + r
#pragma unroll
    for (int it = 0; it < 8; it++) {
#pragma unroll
        for (int r = 0; r < 4; r++) {
            const int n = q0 + lhi * 4 + r;
            op[(size_t)n * 128 + it * 16 + l15] = acc[it][r];
        }
    }
    if (l15 == 0) {
#pragma unroll
        for (int r = 0; r < 4; r++)
            dpart[(size_t)(s * 4 + b) * N + q0 + lhi * 4 + r] = denom[r];
    }
}

// ---------------- combine partials -> Yt bf16 [b][n][ic] ----------------
// grid 784, block 256: 200704 threads, one per (b, n, 8-ic group).
__global__ __launch_bounds__(256) void combine_k(const float* __restrict__ Opart,
                                                 const float* __restrict__ dpart,
                                                 short* __restrict__ Yt)
{
    const int t = blockIdx.x * 256 + threadIdx.x;
    const int ic = (t & 15) * 8;
    const int rest = t >> 4;
    const int n = rest % NTOK;
    const int b = rest / NTOK;
    float sum[8] = {0.f, 0.f, 0.f, 0.f, 0.f, 0.f, 0.f, 0.f};
    float den = 0.f;
#pragma unroll
    for (int s = 0; s < NSPLIT; s++) {
        const size_t base = ((size_t)(s * 4 + b) * NTOK + n) * 128 + ic;
        const f32x4 a = *(const f32x4*)(Opart + base);
        const f32x4 c = *(const f32x4*)(Opart + base + 4);
#pragma unroll
        for (int j = 0; j < 4; j++) { sum[j] += a[j]; sum[4 + j] += c[j]; }
        den += dpart[(size_t)(s * 4 + b) * NTOK + n];
    }
    const float rd = 1.0f / den;
    bf16x8 o;
#pragma unroll
    for (int j = 0; j < 8; j++) o[j] = f2bf(sum[j] * rd);
    *(bf16x8*)(Yt + ((size_t)b * NTOK + n) * 128 + ic) = o;
}

// ---------------- conv_out via MFMA + bias + residual -------------------
__global__ __launch_bounds__(256) void conv_out_m(const short* __restrict__ Yt,
                                                  const short* __restrict__ wupb,
                                                  const float* __restrict__ bup,
                                                  const float* __restrict__ maps,
                                                  float* __restrict__ out)
{
    const int n0 = blockIdx.x * 32, b = blockIdx.y;
    const int wv = __builtin_amdgcn_readfirstlane(threadIdx.x >> 6);
    const int lane = threadIdx.x & 63;
    const int l15 = lane & 15, lhi = lane >> 4;
    const int c0 = wv * 128;
    const short* yp = Yt + (size_t)b * NTOK * 128;

    f32x4 acc[8][2];
#pragma unroll
    for (int g = 0; g < 8; g++)
#pragma unroll
        for (int j = 0; j < 2; j++) acc[g][j] = f32x4{0.f, 0.f, 0.f, 0.f};

#pragma unroll
    for (int ks = 0; ks < 4; ks++) {
        const int k0 = ks * 32 + lhi * 8;
        bf16x8 af[8], bf[2];
#pragma unroll
        for (int g = 0; g < 8; g++)
            af[g] = *(const bf16x8*)(wupb + (size_t)(c0 + g * 16 + l15) * 128 + k0);
#pragma unroll
        for (int j = 0; j < 2; j++)
            bf[j] = *(const bf16x8*)(yp + (size_t)(n0 + j * 16 + l15) * 128 + k0);
#pragma unroll
        for (int g = 0; g < 8; g++)
#pragma unroll
            for (int j = 0; j < 2; j++)
                acc[g][j] = __builtin_amdgcn_mfma_f32_16x16x32_bf16(af[g], bf[j], acc[g][j], 0, 0, 0);
    }
#pragma unroll
    for (int g = 0; g < 8; g++)
#pragma unroll
        for (int j = 0; j < 2; j++)
#pragma unroll
            for (int r = 0; r < 4; r++) {
                const int c = c0 + g * 16 + lhi * 4 + r;
                const int n = n0 + j * 16 + l15;
                const size_t o = ((size_t)b * 512 + c) * NTOK + n;
                out[o] = acc[g][j][r] + bup[c] + maps[o];
            }
}

extern "C" void kernel_launch(void* const* d_in, const int* in_sizes, int n_in,
                              void* d_out, int out_size, void* d_ws, size_t ws_size,
                              hipStream_t stream)
{
    const float* maps    = (const float*)d_in[0];
    const float* w_theta = (const float*)d_in[1];
    const float* w_glob  = (const float*)d_in[5];
    const float* w_up    = (const float*)d_in[7];
    const float* b_up    = (const float*)d_in[8];
    float* out = (float*)d_out;

    // workspace (~19.9 MB): Tb/Gb/Yt overlay dead mapsT region (stream-ordered)
    short* mapsT = (short*)d_ws;               // 4*3136*512 = 6,422,528 shorts
    short* Tb    = mapsT;                      // overlay
    short* Gb    = mapsT + NELEM;              // overlay
    short* Yt    = mapsT + 2 * (size_t)NELEM;  // overlay
    short* Tpre  = mapsT + 6422528;
    short* Gpre  = Tpre + NELEM;
    short* Wb    = Gpre + NELEM;               // 131072 shorts
    short* wupb  = Wb + 131072;                // 65536 shorts
    float* st    = (float*)(wupb + 65536);     // 512 f32
    float* dpart = st + 512;                   // NSPLIT*4*3136 f32 = 200 KB
    float* Opart = out;                        // 25.7 MB partials in d_out (dead until conv_out)

    prep_w    <<<768,            256, 0, stream>>>(w_theta, w_glob, w_up, Wb, wupb);
    transT    <<<dim3(49, 8, 4), 256, 0, stream>>>(maps, mapsT);
    conv_in_m <<<dim3(49, 4, 2), 256, 0, stream>>>(Wb, mapsT, Tpre, Gpre);
    stats_k   <<<256,            256, 0, stream>>>(Tpre, Gpre, st);
    norm_t    <<<dim3(49, 4),    256, 0, stream>>>(Tpre, st, Tb);
    norm_g    <<<784,            256, 0, stream>>>(Gpre, st, Gb);
    attn_k    <<<dim3(49, 4, NSPLIT), 256, 0, stream>>>(Tb, Gb, Opart, dpart);
    combine_k <<<784,            256, 0, stream>>>(Opart, dpart, Yt);
    conv_out_m<<<dim3(98, 4),    256, 0, stream>>>(Yt, wupb, b_up, maps, out);
}

// Round 4
// 117.071 us; speedup vs baseline: 4.6038x; 2.1872x over previous
//
#include <hip/hip_runtime.h>
#include <hip/hip_bf16.h>

// B=4, C=512, IC=128, N=3136
// prep_w     : bf16-ize weights  Wb[256][512] (theta|glob stacked), wupb[512][128]
// transT     : maps f32 [b][c][n] -> mapsT bf16 [b][n][c]   (LDS transpose)
// conv_in_m  : MFMA GEMM -> Tpre/Gpre bf16 [b][ic][n]  (pre-norm; bias cancels in BN)
// stats_k    : per-channel mean / rsqrt(var+eps) over (b,n)
// norm_t     : BN(Tpre) -> Tb bf16 [b][n][ic] (transposed for Q/K frags)
// norm_g     : BN(Gpre) -> Gb bf16 [b][ic][n]
// attn_k     : KV-split (S=4) flash attention, LDS-staged K/V (global_load_lds,
//              XOR-swizzled, double-buffered). Unnormalized partials:
//              Opart[s][b][n][ic] (f32, in d_out) + dpart[s][b][n]
// combine_k  : Yt[b][n][ic] = (sum_s Opart) / (sum_s dpart)  as bf16
// conv_out_m : MFMA GEMM out = w_up@y + b_up + maps (fp32), overwrites d_out

typedef __attribute__((ext_vector_type(8))) short bf16x8;
typedef __attribute__((ext_vector_type(4))) float f32x4;
typedef __attribute__((ext_vector_type(4))) short s16x4;

#define NTOK 3136
#define NELEM 1605632   // 4*128*3136
#define NSPLIT 4

__device__ inline float bf2f(short u) {
    union { unsigned int i; float f; } v;
    v.i = ((unsigned int)(unsigned short)u) << 16;
    return v.f;
}
__device__ inline short f2bf(float x) {
    union { float f; unsigned int i; } v;
    v.f = x;
    unsigned int r = v.i + 0x7FFFu + ((v.i >> 16) & 1u); // RNE
    return (short)(r >> 16);
}
__device__ inline void glds16(const void* g, void* l) {
    __builtin_amdgcn_global_load_lds((const __attribute__((address_space(1))) void*)g,
                                     (__attribute__((address_space(3))) void*)l, 16, 0, 0);
}

// ---------------- prep: weights -> bf16 ---------------------------------
__global__ __launch_bounds__(256) void prep_w(const float* __restrict__ wt,
                                              const float* __restrict__ wg,
                                              const float* __restrict__ wup,
                                              short* __restrict__ Wb,
                                              short* __restrict__ wupb)
{
    const int i = blockIdx.x * 256 + threadIdx.x;
    if (i < 131072) {
        const int r = i >> 9;
        const int c = i & 511;
        const float w = (r < 128) ? wt[(size_t)r * 512 + c] : wg[(size_t)(r - 128) * 512 + c];
        Wb[i] = f2bf(w);
    } else {
        const int j = i - 131072;
        wupb[j] = f2bf(wup[j]);
    }
}

// ---------------- transpose maps -> bf16 [b][n][c] ----------------------
__global__ __launch_bounds__(256) void transT(const float* __restrict__ maps,
                                              short* __restrict__ mapsT)
{
    __shared__ short tile[64][66];
    const int nt = blockIdx.x, cg = blockIdx.y, b = blockIdx.z;
    const int n0 = nt * 64, c0 = cg * 64;
    const int t = threadIdx.x;
    const int nl = t & 63, cq = t >> 6;
#pragma unroll
    for (int i = 0; i < 16; i++) {
        const int cl = i * 4 + cq;
        tile[cl][nl] = f2bf(maps[((size_t)b * 512 + c0 + cl) * NTOK + n0 + nl]);
    }
    __syncthreads();
    const int cl2 = t & 63, nq = t >> 6;
#pragma unroll
    for (int i = 0; i < 16; i++) {
        const int nl2 = i * 4 + nq;
        mapsT[((size_t)b * NTOK + n0 + nl2) * 512 + c0 + cl2] = tile[cl2][nl2];
    }
}

// ---------------- conv_in via MFMA --------------------------------------
__global__ __launch_bounds__(256) void conv_in_m(const short* __restrict__ Wb,
                                                 const short* __restrict__ mapsT,
                                                 short* __restrict__ Tpre,
                                                 short* __restrict__ Gpre)
{
    const int n0 = blockIdx.x * 64, b = blockIdx.y, z = blockIdx.z;
    const int wv = __builtin_amdgcn_readfirstlane(threadIdx.x >> 6);
    const int lane = threadIdx.x & 63;
    const int l15 = lane & 15, lhi = lane >> 4;
    const short* A = Wb + (size_t)z * 128 * 512;
    const short* Bp = mapsT + (size_t)b * NTOK * 512;
    short* out = (z ? Gpre : Tpre) + (size_t)b * 128 * NTOK;
    const int ic0 = wv * 32;

    f32x4 acc[2][4];
#pragma unroll
    for (int g = 0; g < 2; g++)
#pragma unroll
        for (int j = 0; j < 4; j++) acc[g][j] = f32x4{0.f, 0.f, 0.f, 0.f};

    for (int ks = 0; ks < 16; ks++) {
        const int k0 = ks * 32 + lhi * 8;
        bf16x8 af[2], bf[4];
#pragma unroll
        for (int g = 0; g < 2; g++)
            af[g] = *(const bf16x8*)(A + (size_t)(ic0 + g * 16 + l15) * 512 + k0);
#pragma unroll
        for (int j = 0; j < 4; j++)
            bf[j] = *(const bf16x8*)(Bp + (size_t)(n0 + j * 16 + l15) * 512 + k0);
#pragma unroll
        for (int g = 0; g < 2; g++)
#pragma unroll
            for (int j = 0; j < 4; j++)
                acc[g][j] = __builtin_amdgcn_mfma_f32_16x16x32_bf16(af[g], bf[j], acc[g][j], 0, 0, 0);
    }
#pragma unroll
    for (int g = 0; g < 2; g++)
#pragma unroll
        for (int j = 0; j < 4; j++)
#pragma unroll
            for (int r = 0; r < 4; r++) {
                const int ic = ic0 + g * 16 + lhi * 4 + r;
                const int n = n0 + j * 16 + l15;
                out[(size_t)ic * NTOK + n] = f2bf(acc[g][j][r]);
            }
}

// ---------------- stats ---------------------------------------------------
__global__ __launch_bounds__(256) void stats_k(const short* __restrict__ Tpre,
                                               const short* __restrict__ Gpre,
                                               float* __restrict__ st)
{
    const int ch = blockIdx.x;
    const short* src = (ch < 128) ? Tpre : Gpre;
    const int ic = ch & 127;
    const int t = threadIdx.x;
    float s = 0.f, s2 = 0.f;
    for (int b = 0; b < 4; b++) {
        const short* p = src + ((size_t)b * 128 + ic) * NTOK;
        for (int n8 = t; n8 < 392; n8 += 256) {
            bf16x8 v = *(const bf16x8*)(p + n8 * 8);
#pragma unroll
            for (int j = 0; j < 8; j++) { float x = bf2f(v[j]); s += x; s2 += x * x; }
        }
    }
#pragma unroll
    for (int off = 32; off; off >>= 1) { s += __shfl_down(s, off); s2 += __shfl_down(s2, off); }
    __shared__ float ls[2][4];
    const int w = t >> 6;
    if ((t & 63) == 0) { ls[0][w] = s; ls[1][w] = s2; }
    __syncthreads();
    if (t == 0) {
        float S = 0.f, S2 = 0.f;
#pragma unroll
        for (int i = 0; i < 4; i++) { S += ls[0][i]; S2 += ls[1][i]; }
        const float mean = S / 12544.f;
        const float var = S2 / 12544.f - mean * mean;
        st[ch] = mean;
        st[256 + ch] = rsqrtf(var + 1e-5f);
    }
}

// ---------------- BN(theta) + transpose -> Tb [b][n][ic] ----------------
__global__ __launch_bounds__(256) void norm_t(const short* __restrict__ Tpre,
                                              const float* __restrict__ st,
                                              short* __restrict__ Tb)
{
    __shared__ short tile[64][130];
    const int b = blockIdx.y, nt = blockIdx.x;
    const int t = threadIdx.x;
    const int nl = t & 63, ics = t >> 6;
    for (int ic = ics; ic < 128; ic += 4) {
        const float mean = st[ic], rstd = st[256 + ic];
        const float x = bf2f(Tpre[((size_t)b * 128 + ic) * NTOK + nt * 64 + nl]);
        tile[nl][ic] = f2bf((x - mean) * rstd);
    }
    __syncthreads();
    const int ic = t & 127, ns = t >> 7;
    for (int nl2 = ns; nl2 < 64; nl2 += 2) {
        Tb[((size_t)b * NTOK + nt * 64 + nl2) * 128 + ic] = tile[nl2][ic];
    }
}

// ---------------- BN(glob) -> Gb [b][ic][n] -----------------------------
__global__ __launch_bounds__(256) void norm_g(const short* __restrict__ Gpre,
                                              const float* __restrict__ st,
                                              short* __restrict__ Gb)
{
    const size_t base = ((size_t)blockIdx.x * 256 + threadIdx.x) * 8;
    const int ic = (int)((base / NTOK) & 127);
    const float mean = st[128 + ic], rstd = st[256 + 128 + ic];
    bf16x8 v = *(const bf16x8*)(Gpre + base);
    bf16x8 o;
#pragma unroll
    for (int j = 0; j < 8; j++) o[j] = f2bf((bf2f(v[j]) - mean) * rstd);
    *(bf16x8*)(Gb + base) = o;
}

// ---------------- attention: LDS-staged, KV-split partials --------------
// grid (25, B=4, S=4), block 256 = 4 waves; wave owns 32 q-rows (QBLK=128).
// KVBLK=64; split s handles m-tiles s, s+4, ... of 49. K/V double-buffered
// in LDS via global_load_lds (16B), XOR-swizzled (byte ^= (row&7)<<4,
// source pre-swizzled). P per-wave in LDS, same swizzle.
__global__ __launch_bounds__(256) void attn_k(const short* __restrict__ Tb,
                                              const short* __restrict__ Gb,
                                              float* __restrict__ Opart,
                                              float* __restrict__ dpart)
{
    constexpr int N = NTOK;
    const int b = blockIdx.y, s = blockIdx.z;
    const int w = __builtin_amdgcn_readfirstlane(threadIdx.x >> 6);
    const int lane = threadIdx.x & 63;
    const int l15 = lane & 15, lhi = lane >> 4;
    const int q0w = blockIdx.x * 128 + w * 32;

    __shared__ __align__(16) short Kl[2][64][128];  // 32 KB: K tile [m][ic]
    __shared__ __align__(16) short Vl[2][128][64];  // 32 KB: V tile [ic][m]
    __shared__ __align__(16) short Pl[4][32][64];   // 16 KB: per-wave P [q][m]

    const short* tb = Tb + (size_t)b * N * 128;
    const short* gb = Gb + (size_t)b * 128 * N;

    // Q preload (rows clamped for the q-tail; stores masked below)
    bf16x8 qf[2][4];
#pragma unroll
    for (int qs = 0; qs < 2; qs++) {
        int row = q0w + qs * 16 + l15;
        row = row < N ? row : N - 1;
#pragma unroll
        for (int ks = 0; ks < 4; ks++)
            qf[qs][ks] = *(const bf16x8*)(tb + (size_t)row * 128 + ks * 32 + lhi * 8);
    }

    f32x4 acc[2][8];
#pragma unroll
    for (int qs = 0; qs < 2; qs++)
#pragma unroll
        for (int is = 0; is < 8; is++) acc[qs][is] = f32x4{0.f, 0.f, 0.f, 0.f};
    float denom[2][4] = {{0.f, 0.f, 0.f, 0.f}, {0.f, 0.f, 0.f, 0.f}};
    const float inv_n = 1.0f / (float)N;

    auto STAGE = [&](int bufi, int m0) {
        // K: 64 rows x 256B. Wave w stages rows [w*16, w*16+16), 4 instrs x (4 rows).
#pragma unroll
        for (int i = 0; i < 4; i++) {
            const int rb = w * 16 + i * 4;
            const int krow = rb + (lane >> 4);
            const int ksw = ((lane & 15) * 16) ^ ((krow & 7) << 4); // pre-swizzled source
            glds16((const char*)tb + (size_t)(m0 + krow) * 256 + ksw, (char*)&Kl[bufi][rb][0]);
        }
        // V: 128 rows x 128B. Wave w stages rows [w*32, w*32+32), 4 instrs x (8 rows).
#pragma unroll
        for (int i = 0; i < 4; i++) {
            const int rb = w * 32 + i * 8;
            const int vrow = rb + (lane >> 3);
            const int vsw = ((lane & 7) * 16) ^ ((vrow & 7) << 4);
            glds16((const char*)gb + ((size_t)vrow * N + m0) * 2 + vsw, (char*)&Vl[bufi][rb][0]);
        }
    };

    const int nt = (49 - s + NSPLIT - 1) / NSPLIT;
    int mt = s;
    STAGE(0, mt * 64);
    __syncthreads();
    int buf = 0;

    for (int t = 0; t < nt; ++t) {
        if (t + 1 < nt) STAGE(buf ^ 1, (mt + NSPLIT) * 64);

        // --- QK^T : sv[qsub][msub], D: row=lhi*4+r (q), col=l15 (m) ---
        f32x4 sv[2][4];
#pragma unroll
        for (int qs = 0; qs < 2; qs++)
#pragma unroll
            for (int ms = 0; ms < 4; ms++) sv[qs][ms] = f32x4{0.f, 0.f, 0.f, 0.f};
        const int fK = (l15 & 7) << 4;
#pragma unroll
        for (int ms = 0; ms < 4; ms++) {
            const char* kbase = (const char*)&Kl[buf][ms * 16 + l15][0];
#pragma unroll
            for (int ks = 0; ks < 4; ks++) {
                bf16x8 kf = *(const bf16x8*)(kbase + ((ks * 64 + lhi * 16) ^ fK));
                sv[0][ms] = __builtin_amdgcn_mfma_f32_16x16x32_bf16(qf[0][ks], kf, sv[0][ms], 0, 0, 0);
                sv[1][ms] = __builtin_amdgcn_mfma_f32_16x16x32_bf16(qf[1][ks], kf, sv[1][ms], 0, 0, 0);
            }
        }
        // --- exp -> P (swizzled), denom ---
#pragma unroll
        for (int qs = 0; qs < 2; qs++)
#pragma unroll
            for (int r = 0; r < 4; r++) {
                const int prow = qs * 16 + lhi * 4 + r;
                char* pbase = (char*)&Pl[w][prow][0];
                const int pf = (prow & 7) << 4;
#pragma unroll
                for (int ms = 0; ms < 4; ms++) {
                    const float p = __expf(sv[qs][ms][r] * inv_n);
                    denom[qs][r] += p;
                    *(short*)(pbase + (((ms * 16 + l15) * 2) ^ pf)) = f2bf(p);
                }
            }
        // --- PV : A=P rows q, B=V rows ic, k=m (2 k-steps of 32) ---
#pragma unroll
        for (int kp = 0; kp < 2; kp++) {
            const int coff = kp * 64 + lhi * 16;
            bf16x8 pa[2];
#pragma unroll
            for (int qs = 0; qs < 2; qs++)
                pa[qs] = *(const bf16x8*)((const char*)&Pl[w][qs * 16 + l15][0] + (coff ^ fK));
#pragma unroll
            for (int is = 0; is < 8; is++) {
                bf16x8 vf = *(const bf16x8*)((const char*)&Vl[buf][is * 16 + l15][0] + (coff ^ fK));
                acc[0][is] = __builtin_amdgcn_mfma_f32_16x16x32_bf16(pa[0], vf, acc[0][is], 0, 0, 0);
                acc[1][is] = __builtin_amdgcn_mfma_f32_16x16x32_bf16(pa[1], vf, acc[1][is], 0, 0, 0);
            }
        }
        __syncthreads();   // staging for t+1 landed; everyone done reading buf
        buf ^= 1;
        mt += NSPLIT;
    }

    // reduce denom across the 16 m-lanes (l15) of each q-row group
#pragma unroll
    for (int off = 1; off < 16; off <<= 1)
#pragma unroll
        for (int qs = 0; qs < 2; qs++)
#pragma unroll
            for (int r = 0; r < 4; r++) denom[qs][r] += __shfl_xor(denom[qs][r], off);

    float* op = Opart + ((size_t)(s * 4 + b)) * N * 128;
#pragma unroll
    for (int qs = 0; qs < 2; qs++)
#pragma unroll
        for (int is = 0; is < 8; is++)
#pragma unroll
            for (int r = 0; r < 4; r++) {
                const int n = q0w + qs * 16 + lhi * 4 + r;
                if (n < N) op[(size_t)n * 128 + is * 16 + l15] = acc[qs][is][r];
            }
    if (l15 == 0) {
#pragma unroll
        for (int qs = 0; qs < 2; qs++)
#pragma unroll
            for (int r = 0; r < 4; r++) {
                const int n = q0w + qs * 16 + lhi * 4 + r;
                if (n < N) dpart[(size_t)(s * 4 + b) * N + n] = denom[qs][r];
            }
    }
}

// ---------------- combine partials -> Yt bf16 [b][n][ic] ----------------
__global__ __launch_bounds__(256) void combine_k(const float* __restrict__ Opart,
                                                 const float* __restrict__ dpart,
                                                 short* __restrict__ Yt)
{
    const int t = blockIdx.x * 256 + threadIdx.x;
    const int ic = (t & 15) * 8;
    const int rest = t >> 4;
    const int n = rest % NTOK;
    const int b = rest / NTOK;
    float sum[8] = {0.f, 0.f, 0.f, 0.f, 0.f, 0.f, 0.f, 0.f};
    float den = 0.f;
#pragma unroll
    for (int s = 0; s < NSPLIT; s++) {
        const size_t base = ((size_t)(s * 4 + b) * NTOK + n) * 128 + ic;
        const f32x4 a = *(const f32x4*)(Opart + base);
        const f32x4 c = *(const f32x4*)(Opart + base + 4);
#pragma unroll
        for (int j = 0; j < 4; j++) { sum[j] += a[j]; sum[4 + j] += c[j]; }
        den += dpart[(size_t)(s * 4 + b) * NTOK + n];
    }
    const float rd = 1.0f / den;
    bf16x8 o;
#pragma unroll
    for (int j = 0; j < 8; j++) o[j] = f2bf(sum[j] * rd);
    *(bf16x8*)(Yt + ((size_t)b * NTOK + n) * 128 + ic) = o;
}

// ---------------- conv_out via MFMA + bias + residual -------------------
__global__ __launch_bounds__(256) void conv_out_m(const short* __restrict__ Yt,
                                                  const short* __restrict__ wupb,
                                                  const float* __restrict__ bup,
                                                  const float* __restrict__ maps,
                                                  float* __restrict__ out)
{
    const int n0 = blockIdx.x * 32, b = blockIdx.y;
    const int wv = __builtin_amdgcn_readfirstlane(threadIdx.x >> 6);
    const int lane = threadIdx.x & 63;
    const int l15 = lane & 15, lhi = lane >> 4;
    const int c0 = wv * 128;
    const short* yp = Yt + (size_t)b * NTOK * 128;

    f32x4 acc[8][2];
#pragma unroll
    for (int g = 0; g < 8; g++)
#pragma unroll
        for (int j = 0; j < 2; j++) acc[g][j] = f32x4{0.f, 0.f, 0.f, 0.f};

#pragma unroll
    for (int ks = 0; ks < 4; ks++) {
        const int k0 = ks * 32 + lhi * 8;
        bf16x8 af[8], bf[2];
#pragma unroll
        for (int g = 0; g < 8; g++)
            af[g] = *(const bf16x8*)(wupb + (size_t)(c0 + g * 16 + l15) * 128 + k0);
#pragma unroll
        for (int j = 0; j < 2; j++)
            bf[j] = *(const bf16x8*)(yp + (size_t)(n0 + j * 16 + l15) * 128 + k0);
#pragma unroll
        for (int g = 0; g < 8; g++)
#pragma unroll
            for (int j = 0; j < 2; j++)
                acc[g][j] = __builtin_amdgcn_mfma_f32_16x16x32_bf16(af[g], bf[j], acc[g][j], 0, 0, 0);
    }
#pragma unroll
    for (int g = 0; g < 8; g++)
#pragma unroll
        for (int j = 0; j < 2; j++)
#pragma unroll
            for (int r = 0; r < 4; r++) {
                const int c = c0 + g * 16 + lhi * 4 + r;
                const int n = n0 + j * 16 + l15;
                const size_t o = ((size_t)b * 512 + c) * NTOK + n;
                out[o] = acc[g][j][r] + bup[c] + maps[o];
            }
}

extern "C" void kernel_launch(void* const* d_in, const int* in_sizes, int n_in,
                              void* d_out, int out_size, void* d_ws, size_t ws_size,
                              hipStream_t stream)
{
    const float* maps    = (const float*)d_in[0];
    const float* w_theta = (const float*)d_in[1];
    const float* w_glob  = (const float*)d_in[5];
    const float* w_up    = (const float*)d_in[7];
    const float* b_up    = (const float*)d_in[8];
    float* out = (float*)d_out;

    // workspace (~19.9 MB): Tb/Gb/Yt overlay dead mapsT region (stream-ordered)
    short* mapsT = (short*)d_ws;               // 4*3136*512 = 6,422,528 shorts
    short* Tb    = mapsT;                      // overlay
    short* Gb    = mapsT + NELEM;              // overlay
    short* Yt    = mapsT + 2 * (size_t)NELEM;  // overlay
    short* Tpre  = mapsT + 6422528;
    short* Gpre  = Tpre + NELEM;
    short* Wb    = Gpre + NELEM;               // 131072 shorts
    short* wupb  = Wb + 131072;                // 65536 shorts
    float* st    = (float*)(wupb + 65536);     // 512 f32
    float* dpart = st + 512;                   // NSPLIT*4*3136 f32
    float* Opart = out;                        // 25.7 MB partials in d_out (dead until conv_out)

    prep_w    <<<768,            256, 0, stream>>>(w_theta, w_glob, w_up, Wb, wupb);
    transT    <<<dim3(49, 8, 4), 256, 0, stream>>>(maps, mapsT);
    conv_in_m <<<dim3(49, 4, 2), 256, 0, stream>>>(Wb, mapsT, Tpre, Gpre);
    stats_k   <<<256,            256, 0, stream>>>(Tpre, Gpre, st);
    norm_t    <<<dim3(49, 4),    256, 0, stream>>>(Tpre, st, Tb);
    norm_g    <<<784,            256, 0, stream>>>(Gpre, st, Gb);
    attn_k    <<<dim3(25, 4, NSPLIT), 256, 0, stream>>>(Tb, Gb, Opart, dpart);
    combine_k <<<784,            256, 0, stream>>>(Opart, dpart, Yt);
    conv_out_m<<<dim3(98, 4),    256, 0, stream>>>(Yt, wupb, b_up, maps, out);
}

// Round 5
// 98.066 us; speedup vs baseline: 5.4960x; 1.1938x over previous
//
#include <hip/hip_runtime.h>
#include <hip/hip_bf16.h>

// B=4, C=512, IC=128, N=3136
// prep_w     : bf16-ize weights  Wb[256][512] (theta|glob stacked), wupb[512][128]
// conv_in_f  : fused MFMA GEMM from maps (f32) with in-LDS bf16 transpose staging.
//              Writes Tt bf16 [b][n][ic] (theta, pre-norm, TRANSPOSED) and
//              Gpre bf16 [b][ic][n] (glob, pre-norm) + per-block channel partial
//              sums psum/psq (deterministic, no atomics). Bias cancels in BN.
// stats_fin  : reduce partials -> st[512] (means, rstds)
// norm_tg    : elementwise BN -> Tb [b][n][ic], Gb [b][ic][n] (one kernel, z dim)
// attn_k     : KV-split (S=4) flash attention, LDS-staged K/V (global_load_lds,
//              XOR-swizzled, double-buffered). Swapped QK^T (mfma(K,Q)) so P
//              quads are m-contiguous -> b64 P writes, scalar denom.
//              Unnormalized partials: Opart[s][b][n][ic] (f32, in d_out) + dpart.
// combine_k  : Yt[b][n][ic] = (sum_s Opart) / (sum_s dpart)  as bf16
// conv_out_m : MFMA GEMM out = w_up@y + b_up + maps (fp32), overwrites d_out

typedef __attribute__((ext_vector_type(8))) short bf16x8;
typedef __attribute__((ext_vector_type(4))) float f32x4;
typedef __attribute__((ext_vector_type(4))) short s16x4;
typedef __attribute__((ext_vector_type(2))) unsigned int u32x2;

#define NTOK 3136
#define NELEM 1605632   // 4*128*3136
#define NSPLIT 4

__device__ inline float bf2f(short u) {
    union { unsigned int i; float f; } v;
    v.i = ((unsigned int)(unsigned short)u) << 16;
    return v.f;
}
__device__ inline short f2bf(float x) {
    union { float f; unsigned int i; } v;
    v.f = x;
    unsigned int r = v.i + 0x7FFFu + ((v.i >> 16) & 1u); // RNE
    return (short)(r >> 16);
}
__device__ inline unsigned int tbf(float x) { // truncation bf16 (P only)
    union { float f; unsigned int i; } v;
    v.f = x;
    return v.i >> 16;
}
__device__ inline void glds16(const void* g, void* l) {
    __builtin_amdgcn_global_load_lds((const __attribute__((address_space(1))) void*)g,
                                     (__attribute__((address_space(3))) void*)l, 16, 0, 0);
}

// ---------------- prep: weights -> bf16 ---------------------------------
__global__ __launch_bounds__(256) void prep_w(const float* __restrict__ wt,
                                              const float* __restrict__ wg,
                                              const float* __restrict__ wup,
                                              short* __restrict__ Wb,
                                              short* __restrict__ wupb)
{
    const int i = blockIdx.x * 256 + threadIdx.x;
    if (i < 131072) {
        const int r = i >> 9;
        const int c = i & 511;
        const float w = (r < 128) ? wt[(size_t)r * 512 + c] : wg[(size_t)(r - 128) * 512 + c];
        Wb[i] = f2bf(w);
    } else {
        const int j = i - 131072;
        wupb[j] = f2bf(wup[j]);
    }
}

// ---------------- fused input conv --------------------------------------
// grid (98, 4) = (32-n tile, b), block 256 = 4 waves.
// Wave w covers channel rows [w*64, w*64+64) of Wb (w<2: theta, w>=2: glob).
// Per k-chunk (128 c): stage maps chunk f32->bf16 transposed in LDS, MFMA.
__global__ __launch_bounds__(256) void conv_in_f(const float* __restrict__ maps,
                                                 const short* __restrict__ Wb,
                                                 short* __restrict__ Tt,
                                                 short* __restrict__ Gpre,
                                                 float* __restrict__ psum,
                                                 float* __restrict__ psq)
{
    const int nt = blockIdx.x, b = blockIdx.y;
    const int n0 = nt * 32;
    const int t = threadIdx.x;
    const int w = __builtin_amdgcn_readfirstlane(t >> 6);
    const int lane = t & 63;
    const int l15 = lane & 15, lhi = lane >> 4;

    __shared__ short Bt[32][136];   // [n][c-chunk], +8 pad

    const float* mp = maps + (size_t)b * 512 * NTOK + n0;
    const int cl = t >> 3;          // 0..31  (c within 32-row pass)
    const int f4 = t & 7;           // float4 index along n

    f32x4 acc[4][2];
#pragma unroll
    for (int g = 0; g < 4; g++)
#pragma unroll
        for (int j = 0; j < 2; j++) acc[g][j] = f32x4{0.f, 0.f, 0.f, 0.f};

    f32x4 rg[4];
#pragma unroll
    for (int p = 0; p < 4; p++)
        rg[p] = *(const f32x4*)(mp + (size_t)(p * 32 + cl) * NTOK + f4 * 4);

    for (int kc = 0; kc < 4; kc++) {
        __syncthreads();            // previous chunk's reads complete
#pragma unroll
        for (int p = 0; p < 4; p++) {
            const int cc = p * 32 + cl;
#pragma unroll
            for (int i = 0; i < 4; i++) Bt[f4 * 4 + i][cc] = f2bf(rg[p][i]);
        }
        if (kc < 3) {
#pragma unroll
            for (int p = 0; p < 4; p++)
                rg[p] = *(const f32x4*)(mp + (size_t)((kc + 1) * 128 + p * 32 + cl) * NTOK + f4 * 4);
        }
        __syncthreads();
#pragma unroll
        for (int ks = 0; ks < 4; ks++) {
            bf16x8 af[4], bv[2];
#pragma unroll
            for (int g = 0; g < 4; g++)
                af[g] = *(const bf16x8*)(Wb + (size_t)(w * 64 + g * 16 + l15) * 512 + kc * 128 + ks * 32 + lhi * 8);
#pragma unroll
            for (int j = 0; j < 2; j++)
                bv[j] = *(const bf16x8*)(&Bt[j * 16 + l15][ks * 32 + lhi * 8]);
#pragma unroll
            for (int g = 0; g < 4; g++)
#pragma unroll
                for (int j = 0; j < 2; j++)
                    acc[g][j] = __builtin_amdgcn_mfma_f32_16x16x32_bf16(af[g], bv[j], acc[g][j], 0, 0, 0);
        }
    }

    // ---- outputs. D layout: col(l15)=n_local, row(lhi*4+r)=ch_local ----
    if (w < 2) {
        // theta -> Tt [b][n][ic] : 4 consecutive ic per lane -> 8B stores
#pragma unroll
        for (int g = 0; g < 4; g++)
#pragma unroll
            for (int j = 0; j < 2; j++) {
                s16x4 v;
#pragma unroll
                for (int r = 0; r < 4; r++) v[r] = f2bf(acc[g][j][r]);
                *(s16x4*)(Tt + ((size_t)b * NTOK + n0 + j * 16 + l15) * 128 + w * 64 + g * 16 + lhi * 4) = v;
            }
    } else {
        // glob -> Gpre [b][ic][n]
#pragma unroll
        for (int g = 0; g < 4; g++)
#pragma unroll
            for (int j = 0; j < 2; j++)
#pragma unroll
                for (int r = 0; r < 4; r++) {
                    const int icg = (w - 2) * 64 + g * 16 + lhi * 4 + r;
                    Gpre[((size_t)b * 128 + icg) * NTOK + n0 + j * 16 + l15] = f2bf(acc[g][j][r]);
                }
    }
    // ---- stats partials: sum over this block's 32 n per channel ----
#pragma unroll
    for (int g = 0; g < 4; g++)
#pragma unroll
        for (int r = 0; r < 4; r++) {
            float s = acc[g][0][r] + acc[g][1][r];
            float q = acc[g][0][r] * acc[g][0][r] + acc[g][1][r] * acc[g][1][r];
#pragma unroll
            for (int off = 1; off < 16; off <<= 1) {
                s += __shfl_xor(s, off);
                q += __shfl_xor(q, off);
            }
            if (l15 == 0) {
                const int ch = w * 64 + g * 16 + lhi * 4 + r;  // 0-127 theta, 128-255 glob
                psum[(size_t)ch * 392 + b * 98 + nt] = s;
                psq [(size_t)ch * 392 + b * 98 + nt] = q;
            }
        }
}

// ---------------- finalize stats ----------------------------------------
// grid 256 (one channel per block), block 64.
__global__ __launch_bounds__(64) void stats_fin(const float* __restrict__ psum,
                                                const float* __restrict__ psq,
                                                float* __restrict__ st)
{
    const int ch = blockIdx.x;
    const int lane = threadIdx.x;
    float s = 0.f, q = 0.f;
    for (int i = lane; i < 392; i += 64) {
        s += psum[(size_t)ch * 392 + i];
        q += psq [(size_t)ch * 392 + i];
    }
#pragma unroll
    for (int off = 32; off; off >>= 1) { s += __shfl_xor(s, off); q += __shfl_xor(q, off); }
    if (lane == 0) {
        const float mean = s / 12544.f;
        const float var = q / 12544.f - mean * mean;
        st[ch] = mean;
        st[256 + ch] = rsqrtf(var + 1e-5f);
    }
}

// ---------------- BN both branches, elementwise -------------------------
// grid (784, 2), block 256, 8 elems/thread. z=0: Tt->Tb ([b][n][ic], ic fastest)
// z=1: Gpre->Gb ([b][ic][n], n fastest).
__global__ __launch_bounds__(256) void norm_tg(const short* __restrict__ Tt,
                                               const short* __restrict__ Gpre,
                                               const float* __restrict__ st,
                                               short* __restrict__ Tb,
                                               short* __restrict__ Gb)
{
    const size_t base = ((size_t)blockIdx.x * 256 + threadIdx.x) * 8;
    if (blockIdx.y == 0) {
        const int ic = (int)(base & 127);
        const f32x4 m0 = *(const f32x4*)(st + ic);
        const f32x4 m1 = *(const f32x4*)(st + ic + 4);
        const f32x4 r0 = *(const f32x4*)(st + 256 + ic);
        const f32x4 r1 = *(const f32x4*)(st + 256 + ic + 4);
        bf16x8 v = *(const bf16x8*)(Tt + base);
        bf16x8 o;
#pragma unroll
        for (int j = 0; j < 4; j++) o[j] = f2bf((bf2f(v[j]) - m0[j]) * r0[j]);
#pragma unroll
        for (int j = 0; j < 4; j++) o[4 + j] = f2bf((bf2f(v[4 + j]) - m1[j]) * r1[j]);
        *(bf16x8*)(Tb + base) = o;
    } else {
        const int ic = (int)((base / NTOK) & 127);
        const float mean = st[128 + ic], rstd = st[384 + ic];
        bf16x8 v = *(const bf16x8*)(Gpre + base);
        bf16x8 o;
#pragma unroll
        for (int j = 0; j < 8; j++) o[j] = f2bf((bf2f(v[j]) - mean) * rstd);
        *(bf16x8*)(Gb + base) = o;
    }
}

// ---------------- attention: LDS-staged, KV-split partials --------------
// grid (25, B=4, S=4), block 256 = 4 waves; wave owns 32 q-rows (QBLK=128).
// KVBLK=64. Swapped QK^T: sv = mfma(K, Q) -> col(l15)=q_local, row(lhi*4+r)=m_local.
// P quads m-contiguous -> ds_write_b64 (conflict-free with XOR swizzle).
__global__ __launch_bounds__(256) void attn_k(const short* __restrict__ Tb,
                                              const short* __restrict__ Gb,
                                              float* __restrict__ Opart,
                                              float* __restrict__ dpart)
{
    constexpr int N = NTOK;
    const int b = blockIdx.y, s = blockIdx.z;
    const int w = __builtin_amdgcn_readfirstlane(threadIdx.x >> 6);
    const int lane = threadIdx.x & 63;
    const int l15 = lane & 15, lhi = lane >> 4;
    const int q0w = blockIdx.x * 128 + w * 32;

    __shared__ __align__(16) short Kl[2][64][128];  // 32 KB: K tile [m][ic]
    __shared__ __align__(16) short Vl[2][128][64];  // 32 KB: V tile [ic][m]
    __shared__ __align__(16) short Pl[4][32][64];   // 16 KB: per-wave P [q][m]

    const short* tb = Tb + (size_t)b * N * 128;
    const short* gb = Gb + (size_t)b * 128 * N;

    // Q preload (rows clamped for the q-tail; stores masked below)
    bf16x8 qf[2][4];
#pragma unroll
    for (int qs = 0; qs < 2; qs++) {
        int row = q0w + qs * 16 + l15;
        row = row < N ? row : N - 1;
#pragma unroll
        for (int ks = 0; ks < 4; ks++)
            qf[qs][ks] = *(const bf16x8*)(tb + (size_t)row * 128 + ks * 32 + lhi * 8);
    }

    f32x4 acc[2][8];
#pragma unroll
    for (int qs = 0; qs < 2; qs++)
#pragma unroll
        for (int is = 0; is < 8; is++) acc[qs][is] = f32x4{0.f, 0.f, 0.f, 0.f};
    float denom[2] = {0.f, 0.f};
    const float inv_n = 1.0f / (float)N;

    auto STAGE = [&](int bufi, int m0) {
#pragma unroll
        for (int i = 0; i < 4; i++) {
            const int rb = w * 16 + i * 4;
            const int krow = rb + (lane >> 4);
            const int ksw = ((lane & 15) * 16) ^ ((krow & 7) << 4); // pre-swizzled source
            glds16((const char*)tb + (size_t)(m0 + krow) * 256 + ksw, (char*)&Kl[bufi][rb][0]);
        }
#pragma unroll
        for (int i = 0; i < 4; i++) {
            const int rb = w * 32 + i * 8;
            const int vrow = rb + (lane >> 3);
            const int vsw = ((lane & 7) * 16) ^ ((vrow & 7) << 4);
            glds16((const char*)gb + ((size_t)vrow * N + m0) * 2 + vsw, (char*)&Vl[bufi][rb][0]);
        }
    };

    const int nt = (49 - s + NSPLIT - 1) / NSPLIT;
    int mt = s;
    STAGE(0, mt * 64);
    __syncthreads();
    int buf = 0;

    const int fK = (l15 & 7) << 4;

    for (int t = 0; t < nt; ++t) {
        if (t + 1 < nt) STAGE(buf ^ 1, (mt + NSPLIT) * 64);

        // --- QK^T (swapped): sv[qs][ms]; col=q_local(l15), row=m_local(lhi*4+r)
        f32x4 sv[2][4];
#pragma unroll
        for (int qs = 0; qs < 2; qs++)
#pragma unroll
            for (int ms = 0; ms < 4; ms++) sv[qs][ms] = f32x4{0.f, 0.f, 0.f, 0.f};
#pragma unroll
        for (int ms = 0; ms < 4; ms++) {
            const char* kbase = (const char*)&Kl[buf][ms * 16 + l15][0];
#pragma unroll
            for (int ks = 0; ks < 4; ks++) {
                bf16x8 kf = *(const bf16x8*)(kbase + ((ks * 64 + lhi * 16) ^ fK));
                sv[0][ms] = __builtin_amdgcn_mfma_f32_16x16x32_bf16(kf, qf[0][ks], sv[0][ms], 0, 0, 0);
                sv[1][ms] = __builtin_amdgcn_mfma_f32_16x16x32_bf16(kf, qf[1][ks], sv[1][ms], 0, 0, 0);
            }
        }
        // --- exp -> P[q][m] (b64 quad writes, swizzle ^((q&7)<<4) == fK), denom scalar
#pragma unroll
        for (int qs = 0; qs < 2; qs++) {
            char* pbase = (char*)&Pl[w][qs * 16 + l15][0];
#pragma unroll
            for (int ms = 0; ms < 4; ms++) {
                const float p0 = __expf(sv[qs][ms][0] * inv_n);
                const float p1 = __expf(sv[qs][ms][1] * inv_n);
                const float p2 = __expf(sv[qs][ms][2] * inv_n);
                const float p3 = __expf(sv[qs][ms][3] * inv_n);
                denom[qs] += (p0 + p1) + (p2 + p3);
                u32x2 u;
                u[0] = tbf(p0) | (tbf(p1) << 16);
                u[1] = tbf(p2) | (tbf(p3) << 16);
                *(u32x2*)(pbase + ((ms * 32 + lhi * 8) ^ fK)) = u;
            }
        }
        // --- PV : A=P rows q, B=V rows ic, k=m (2 k-steps of 32) ---
#pragma unroll
        for (int kp = 0; kp < 2; kp++) {
            const int coff = kp * 64 + lhi * 16;
            bf16x8 pa[2];
#pragma unroll
            for (int qs = 0; qs < 2; qs++)
                pa[qs] = *(const bf16x8*)((const char*)&Pl[w][qs * 16 + l15][0] + (coff ^ fK));
#pragma unroll
            for (int is = 0; is < 8; is++) {
                bf16x8 vf = *(const bf16x8*)((const char*)&Vl[buf][is * 16 + l15][0] + (coff ^ fK));
                acc[0][is] = __builtin_amdgcn_mfma_f32_16x16x32_bf16(pa[0], vf, acc[0][is], 0, 0, 0);
                acc[1][is] = __builtin_amdgcn_mfma_f32_16x16x32_bf16(pa[1], vf, acc[1][is], 0, 0, 0);
            }
        }
        __syncthreads();
        buf ^= 1;
        mt += NSPLIT;
    }

    // denom: per-lane q = qs*16+l15; combine the 4 lhi replicas
#pragma unroll
    for (int qs = 0; qs < 2; qs++) {
        denom[qs] += __shfl_xor(denom[qs], 16);
        denom[qs] += __shfl_xor(denom[qs], 32);
    }

    float* op = Opart + ((size_t)(s * 4 + b)) * N * 128;
    // acc layout: ic = is*16 + l15 (B row), n = q0w + qs*16 + lhi*4 + r (A row)
#pragma unroll
    for (int qs = 0; qs < 2; qs++)
#pragma unroll
        for (int is = 0; is < 8; is++)
#pragma unroll
            for (int r = 0; r < 4; r++) {
                const int n = q0w + qs * 16 + lhi * 4 + r;
                if (n < N) op[(size_t)n * 128 + is * 16 + l15] = acc[qs][is][r];
            }
    if (lhi == 0) {
#pragma unroll
        for (int qs = 0; qs < 2; qs++) {
            const int n = q0w + qs * 16 + l15;
            if (n < N) dpart[(size_t)(s * 4 + b) * N + n] = denom[qs];
        }
    }
}

// ---------------- combine partials -> Yt bf16 [b][n][ic] ----------------
__global__ __launch_bounds__(256) void combine_k(const float* __restrict__ Opart,
                                                 const float* __restrict__ dpart,
                                                 short* __restrict__ Yt)
{
    const int t = blockIdx.x * 256 + threadIdx.x;
    const int ic = (t & 15) * 8;
    const int rest = t >> 4;
    const int n = rest % NTOK;
    const int b = rest / NTOK;
    float sum[8] = {0.f, 0.f, 0.f, 0.f, 0.f, 0.f, 0.f, 0.f};
    float den = 0.f;
#pragma unroll
    for (int s = 0; s < NSPLIT; s++) {
        const size_t base = ((size_t)(s * 4 + b) * NTOK + n) * 128 + ic;
        const f32x4 a = *(const f32x4*)(Opart + base);
        const f32x4 c = *(const f32x4*)(Opart + base + 4);
#pragma unroll
        for (int j = 0; j < 4; j++) { sum[j] += a[j]; sum[4 + j] += c[j]; }
        den += dpart[(size_t)(s * 4 + b) * NTOK + n];
    }
    const float rd = 1.0f / den;
    bf16x8 o;
#pragma unroll
    for (int j = 0; j < 8; j++) o[j] = f2bf(sum[j] * rd);
    *(bf16x8*)(Yt + ((size_t)b * NTOK + n) * 128 + ic) = o;
}

// ---------------- conv_out via MFMA + bias + residual -------------------
__global__ __launch_bounds__(256) void conv_out_m(const short* __restrict__ Yt,
                                                  const short* __restrict__ wupb,
                                                  const float* __restrict__ bup,
                                                  const float* __restrict__ maps,
                                                  float* __restrict__ out)
{
    const int n0 = blockIdx.x * 32, b = blockIdx.y;
    const int wv = __builtin_amdgcn_readfirstlane(threadIdx.x >> 6);
    const int lane = threadIdx.x & 63;
    const int l15 = lane & 15, lhi = lane >> 4;
    const int c0 = wv * 128;
    const short* yp = Yt + (size_t)b * NTOK * 128;

    f32x4 acc[8][2];
#pragma unroll
    for (int g = 0; g < 8; g++)
#pragma unroll
        for (int j = 0; j < 2; j++) acc[g][j] = f32x4{0.f, 0.f, 0.f, 0.f};

#pragma unroll
    for (int ks = 0; ks < 4; ks++) {
        const int k0 = ks * 32 + lhi * 8;
        bf16x8 af[8], bf[2];
#pragma unroll
        for (int g = 0; g < 8; g++)
            af[g] = *(const bf16x8*)(wupb + (size_t)(c0 + g * 16 + l15) * 128 + k0);
#pragma unroll
        for (int j = 0; j < 2; j++)
            bf[j] = *(const bf16x8*)(yp + (size_t)(n0 + j * 16 + l15) * 128 + k0);
#pragma unroll
        for (int g = 0; g < 8; g++)
#pragma unroll
            for (int j = 0; j < 2; j++)
                acc[g][j] = __builtin_amdgcn_mfma_f32_16x16x32_bf16(af[g], bf[j], acc[g][j], 0, 0, 0);
    }
#pragma unroll
    for (int g = 0; g < 8; g++)
#pragma unroll
        for (int j = 0; j < 2; j++)
#pragma unroll
            for (int r = 0; r < 4; r++) {
                const int c = c0 + g * 16 + lhi * 4 + r;
                const int n = n0 + j * 16 + l15;
                const size_t o = ((size_t)b * 512 + c) * NTOK + n;
                out[o] = acc[g][j][r] + bup[c] + maps[o];
            }
}

extern "C" void kernel_launch(void* const* d_in, const int* in_sizes, int n_in,
                              void* d_out, int out_size, void* d_ws, size_t ws_size,
                              hipStream_t stream)
{
    const float* maps    = (const float*)d_in[0];
    const float* w_theta = (const float*)d_in[1];
    const float* w_glob  = (const float*)d_in[5];
    const float* w_up    = (const float*)d_in[7];
    const float* b_up    = (const float*)d_in[8];
    float* out = (float*)d_out;

    // workspace (~17.5 MB), no overlays
    short* Tt    = (short*)d_ws;               // NELEM (theta pre-norm, [b][n][ic])
    short* Gpre  = Tt + NELEM;                 // NELEM (glob pre-norm, [b][ic][n])
    short* Tb    = Gpre + NELEM;               // NELEM
    short* Gb    = Tb + NELEM;                 // NELEM
    short* Yt    = Gb + NELEM;                 // NELEM
    short* Wb    = Yt + NELEM;                 // 131072 shorts
    short* wupb  = Wb + 131072;                // 65536 shorts
    float* st    = (float*)(wupb + 65536);     // 512 f32
    float* psum  = st + 512;                   // 256*392 f32
    float* psq   = psum + 100352;              // 256*392 f32
    float* dpart = psq + 100352;               // NSPLIT*4*3136 f32
    float* Opart = out;                        // 25.7 MB partials in d_out (dead until conv_out)

    prep_w    <<<768,             256, 0, stream>>>(w_theta, w_glob, w_up, Wb, wupb);
    conv_in_f <<<dim3(98, 4),     256, 0, stream>>>(maps, Wb, Tt, Gpre, psum, psq);
    stats_fin <<<256,             64,  0, stream>>>(psum, psq, st);
    norm_tg   <<<dim3(784, 2),    256, 0, stream>>>(Tt, Gpre, st, Tb, Gb);
    attn_k    <<<dim3(25, 4, NSPLIT), 256, 0, stream>>>(Tb, Gb, Opart, dpart);
    combine_k <<<784,             256, 0, stream>>>(Opart, dpart, Yt);
    conv_out_m<<<dim3(98, 4),     256, 0, stream>>>(Yt, wupb, b_up, maps, out);
}

// Round 6
// 91.876 us; speedup vs baseline: 5.8663x; 1.0674x over previous
//
#include <hip/hip_runtime.h>
#include <hip/hip_bf16.h>

// B=4, C=512, IC=128, N=3136
// prep_w     : bf16-ize weights  Wb[256][512] (theta|glob stacked), wupb[512][128]
// conv_in_f  : fused MFMA GEMM from maps (f32) with in-LDS bf16 transpose staging.
//              Writes Tt bf16 [b][n][ic] (theta pre-norm, transposed) and
//              Gpre bf16 [b][ic][n] (glob pre-norm) + per-block channel partials.
// stats_fin  : reduce partials -> st[512] (means, rstds)
// attn_k     : KV-split (S=4) flash attention. BN folded by algebra:
//                K = raw Tt  (mean-term is a softmax row-constant -> drops)
//                Q = (theta - mu)*rho^2 applied in-register at load
//                V = raw Gpre (BN applied post-hoc: y = rho*(P@G - mu), sum P = 1)
//              LDS-staged K/V (global_load_lds, XOR-swizzled, double-buffered),
//              swapped QK^T. Partials: Opart[s][b][n][ic] f32 (in d_ws) + dpart.
// conv_out_f : fused combine + de-norm + MFMA GEMM + bias + residual -> out.

typedef __attribute__((ext_vector_type(8))) short bf16x8;
typedef __attribute__((ext_vector_type(4))) float f32x4;
typedef __attribute__((ext_vector_type(4))) short s16x4;
typedef __attribute__((ext_vector_type(2))) unsigned int u32x2;

#define NTOK 3136
#define NELEM 1605632   // 4*128*3136
#define NSPLIT 4

__device__ inline float bf2f(short u) {
    union { unsigned int i; float f; } v;
    v.i = ((unsigned int)(unsigned short)u) << 16;
    return v.f;
}
__device__ inline short f2bf(float x) {
    union { float f; unsigned int i; } v;
    v.f = x;
    unsigned int r = v.i + 0x7FFFu + ((v.i >> 16) & 1u); // RNE
    return (short)(r >> 16);
}
__device__ inline unsigned int tbf(float x) { // truncation bf16 (P only)
    union { float f; unsigned int i; } v;
    v.f = x;
    return v.i >> 16;
}
__device__ inline void glds16(const void* g, void* l) {
    __builtin_amdgcn_global_load_lds((const __attribute__((address_space(1))) void*)g,
                                     (__attribute__((address_space(3))) void*)l, 16, 0, 0);
}

// ---------------- prep: weights -> bf16 ---------------------------------
__global__ __launch_bounds__(256) void prep_w(const float* __restrict__ wt,
                                              const float* __restrict__ wg,
                                              const float* __restrict__ wup,
                                              short* __restrict__ Wb,
                                              short* __restrict__ wupb)
{
    const int i = blockIdx.x * 256 + threadIdx.x;
    if (i < 131072) {
        const int r = i >> 9;
        const int c = i & 511;
        const float w = (r < 128) ? wt[(size_t)r * 512 + c] : wg[(size_t)(r - 128) * 512 + c];
        Wb[i] = f2bf(w);
    } else {
        const int j = i - 131072;
        wupb[j] = f2bf(wup[j]);
    }
}

// ---------------- fused input conv --------------------------------------
// grid (98, 4) = (32-n tile, b), block 256 = 4 waves.
__global__ __launch_bounds__(256) void conv_in_f(const float* __restrict__ maps,
                                                 const short* __restrict__ Wb,
                                                 short* __restrict__ Tt,
                                                 short* __restrict__ Gpre,
                                                 float* __restrict__ psum,
                                                 float* __restrict__ psq)
{
    const int nt = blockIdx.x, b = blockIdx.y;
    const int n0 = nt * 32;
    const int t = threadIdx.x;
    const int w = __builtin_amdgcn_readfirstlane(t >> 6);
    const int lane = t & 63;
    const int l15 = lane & 15, lhi = lane >> 4;

    __shared__ short Bt[32][136];   // [n][c-chunk], +8 pad

    const float* mp = maps + (size_t)b * 512 * NTOK + n0;
    const int cl = t >> 3;          // 0..31
    const int f4 = t & 7;           // float4 index along n

    f32x4 acc[4][2];
#pragma unroll
    for (int g = 0; g < 4; g++)
#pragma unroll
        for (int j = 0; j < 2; j++) acc[g][j] = f32x4{0.f, 0.f, 0.f, 0.f};

    f32x4 rg[4];
#pragma unroll
    for (int p = 0; p < 4; p++)
        rg[p] = *(const f32x4*)(mp + (size_t)(p * 32 + cl) * NTOK + f4 * 4);

    for (int kc = 0; kc < 4; kc++) {
        __syncthreads();
#pragma unroll
        for (int p = 0; p < 4; p++) {
            const int cc = p * 32 + cl;
#pragma unroll
            for (int i = 0; i < 4; i++) Bt[f4 * 4 + i][cc] = f2bf(rg[p][i]);
        }
        if (kc < 3) {
#pragma unroll
            for (int p = 0; p < 4; p++)
                rg[p] = *(const f32x4*)(mp + (size_t)((kc + 1) * 128 + p * 32 + cl) * NTOK + f4 * 4);
        }
        __syncthreads();
#pragma unroll
        for (int ks = 0; ks < 4; ks++) {
            bf16x8 af[4], bv[2];
#pragma unroll
            for (int g = 0; g < 4; g++)
                af[g] = *(const bf16x8*)(Wb + (size_t)(w * 64 + g * 16 + l15) * 512 + kc * 128 + ks * 32 + lhi * 8);
#pragma unroll
            for (int j = 0; j < 2; j++)
                bv[j] = *(const bf16x8*)(&Bt[j * 16 + l15][ks * 32 + lhi * 8]);
#pragma unroll
            for (int g = 0; g < 4; g++)
#pragma unroll
                for (int j = 0; j < 2; j++)
                    acc[g][j] = __builtin_amdgcn_mfma_f32_16x16x32_bf16(af[g], bv[j], acc[g][j], 0, 0, 0);
        }
    }

    // ---- outputs. D layout: col(l15)=n_local, row(lhi*4+r)=ch_local ----
    if (w < 2) {
#pragma unroll
        for (int g = 0; g < 4; g++)
#pragma unroll
            for (int j = 0; j < 2; j++) {
                s16x4 v;
#pragma unroll
                for (int r = 0; r < 4; r++) v[r] = f2bf(acc[g][j][r]);
                *(s16x4*)(Tt + ((size_t)b * NTOK + n0 + j * 16 + l15) * 128 + w * 64 + g * 16 + lhi * 4) = v;
            }
    } else {
#pragma unroll
        for (int g = 0; g < 4; g++)
#pragma unroll
            for (int j = 0; j < 2; j++)
#pragma unroll
                for (int r = 0; r < 4; r++) {
                    const int icg = (w - 2) * 64 + g * 16 + lhi * 4 + r;
                    Gpre[((size_t)b * 128 + icg) * NTOK + n0 + j * 16 + l15] = f2bf(acc[g][j][r]);
                }
    }
#pragma unroll
    for (int g = 0; g < 4; g++)
#pragma unroll
        for (int r = 0; r < 4; r++) {
            float s = acc[g][0][r] + acc[g][1][r];
            float q = acc[g][0][r] * acc[g][0][r] + acc[g][1][r] * acc[g][1][r];
#pragma unroll
            for (int off = 1; off < 16; off <<= 1) {
                s += __shfl_xor(s, off);
                q += __shfl_xor(q, off);
            }
            if (l15 == 0) {
                const int ch = w * 64 + g * 16 + lhi * 4 + r;  // 0-127 theta, 128-255 glob
                psum[(size_t)ch * 392 + b * 98 + nt] = s;
                psq [(size_t)ch * 392 + b * 98 + nt] = q;
            }
        }
}

// ---------------- finalize stats ----------------------------------------
__global__ __launch_bounds__(64) void stats_fin(const float* __restrict__ psum,
                                                const float* __restrict__ psq,
                                                float* __restrict__ st)
{
    const int ch = blockIdx.x;
    const int lane = threadIdx.x;
    float s = 0.f, q = 0.f;
    for (int i = lane; i < 392; i += 64) {
        s += psum[(size_t)ch * 392 + i];
        q += psq [(size_t)ch * 392 + i];
    }
#pragma unroll
    for (int off = 32; off; off >>= 1) { s += __shfl_xor(s, off); q += __shfl_xor(q, off); }
    if (lane == 0) {
        const float mean = s / 12544.f;
        const float var = q / 12544.f - mean * mean;
        st[ch] = mean;
        st[256 + ch] = rsqrtf(var + 1e-5f);
    }
}

// ---------------- attention: BN-folded, LDS-staged, KV-split ------------
// grid (25, B=4, S=4), block 256 = 4 waves; wave owns 32 q-rows (QBLK=128).
// K = raw Tt, V = raw Gpre; Q = (theta - mu)*rho^2 (softmax-equivalent).
__global__ __launch_bounds__(256) void attn_k(const short* __restrict__ Tt,
                                              const short* __restrict__ Gpre,
                                              const float* __restrict__ st,
                                              float* __restrict__ Opart,
                                              float* __restrict__ dpart)
{
    constexpr int N = NTOK;
    const int b = blockIdx.y, s = blockIdx.z;
    const int w = __builtin_amdgcn_readfirstlane(threadIdx.x >> 6);
    const int lane = threadIdx.x & 63;
    const int l15 = lane & 15, lhi = lane >> 4;
    const int q0w = blockIdx.x * 128 + w * 32;

    __shared__ __align__(16) short Kl[2][64][128];  // 32 KB: K tile [m][ic]
    __shared__ __align__(16) short Vl[2][128][64];  // 32 KB: V tile [ic][m]
    __shared__ __align__(16) short Pl[4][32][64];   // 16 KB: per-wave P [q][m]

    const short* tb = Tt + (size_t)b * N * 128;
    const short* gb = Gpre + (size_t)b * 128 * N;

    // Q preload with in-register BN fold: q = (t - mu) * rho^2
    bf16x8 qf[2][4];
#pragma unroll
    for (int qs = 0; qs < 2; qs++) {
        int row = q0w + qs * 16 + l15;
        row = row < N ? row : N - 1;
#pragma unroll
        for (int ks = 0; ks < 4; ks++) {
            const bf16x8 v = *(const bf16x8*)(tb + (size_t)row * 128 + ks * 32 + lhi * 8);
            const int c0 = ks * 32 + lhi * 8;
            const f32x4 mA = *(const f32x4*)(st + c0);
            const f32x4 mB = *(const f32x4*)(st + c0 + 4);
            const f32x4 rA = *(const f32x4*)(st + 256 + c0);
            const f32x4 rB = *(const f32x4*)(st + 256 + c0 + 4);
            bf16x8 q;
#pragma unroll
            for (int j = 0; j < 4; j++) q[j] = f2bf((bf2f(v[j]) - mA[j]) * (rA[j] * rA[j]));
#pragma unroll
            for (int j = 0; j < 4; j++) q[4 + j] = f2bf((bf2f(v[4 + j]) - mB[j]) * (rB[j] * rB[j]));
            qf[qs][ks] = q;
        }
    }

    f32x4 acc[2][8];
#pragma unroll
    for (int qs = 0; qs < 2; qs++)
#pragma unroll
        for (int is = 0; is < 8; is++) acc[qs][is] = f32x4{0.f, 0.f, 0.f, 0.f};
    float denom[2] = {0.f, 0.f};
    const float inv_n = 1.0f / (float)N;

    auto STAGE = [&](int bufi, int m0) {
#pragma unroll
        for (int i = 0; i < 4; i++) {
            const int rb = w * 16 + i * 4;
            const int krow = rb + (lane >> 4);
            const int ksw = ((lane & 15) * 16) ^ ((krow & 7) << 4); // pre-swizzled source
            glds16((const char*)tb + (size_t)(m0 + krow) * 256 + ksw, (char*)&Kl[bufi][rb][0]);
        }
#pragma unroll
        for (int i = 0; i < 4; i++) {
            const int rb = w * 32 + i * 8;
            const int vrow = rb + (lane >> 3);
            const int vsw = ((lane & 7) * 16) ^ ((vrow & 7) << 4);
            glds16((const char*)gb + ((size_t)vrow * N + m0) * 2 + vsw, (char*)&Vl[bufi][rb][0]);
        }
    };

    const int nt = (49 - s + NSPLIT - 1) / NSPLIT;
    int mt = s;
    STAGE(0, mt * 64);
    __syncthreads();
    int buf = 0;

    const int fK = (l15 & 7) << 4;

    for (int t = 0; t < nt; ++t) {
        if (t + 1 < nt) STAGE(buf ^ 1, (mt + NSPLIT) * 64);

        // --- QK^T (swapped): col=q_local(l15), row=m_local(lhi*4+r) ---
        f32x4 sv[2][4];
#pragma unroll
        for (int qs = 0; qs < 2; qs++)
#pragma unroll
            for (int ms = 0; ms < 4; ms++) sv[qs][ms] = f32x4{0.f, 0.f, 0.f, 0.f};
#pragma unroll
        for (int ms = 0; ms < 4; ms++) {
            const char* kbase = (const char*)&Kl[buf][ms * 16 + l15][0];
#pragma unroll
            for (int ks = 0; ks < 4; ks++) {
                bf16x8 kf = *(const bf16x8*)(kbase + ((ks * 64 + lhi * 16) ^ fK));
                sv[0][ms] = __builtin_amdgcn_mfma_f32_16x16x32_bf16(kf, qf[0][ks], sv[0][ms], 0, 0, 0);
                sv[1][ms] = __builtin_amdgcn_mfma_f32_16x16x32_bf16(kf, qf[1][ks], sv[1][ms], 0, 0, 0);
            }
        }
        // --- exp -> P[q][m] (b64 quad writes), denom scalar ---
#pragma unroll
        for (int qs = 0; qs < 2; qs++) {
            char* pbase = (char*)&Pl[w][qs * 16 + l15][0];
#pragma unroll
            for (int ms = 0; ms < 4; ms++) {
                const float p0 = __expf(sv[qs][ms][0] * inv_n);
                const float p1 = __expf(sv[qs][ms][1] * inv_n);
                const float p2 = __expf(sv[qs][ms][2] * inv_n);
                const float p3 = __expf(sv[qs][ms][3] * inv_n);
                denom[qs] += (p0 + p1) + (p2 + p3);
                u32x2 u;
                u[0] = tbf(p0) | (tbf(p1) << 16);
                u[1] = tbf(p2) | (tbf(p3) << 16);
                *(u32x2*)(pbase + ((ms * 32 + lhi * 8) ^ fK)) = u;
            }
        }
        // --- PV ---
#pragma unroll
        for (int kp = 0; kp < 2; kp++) {
            const int coff = kp * 64 + lhi * 16;
            bf16x8 pa[2];
#pragma unroll
            for (int qs = 0; qs < 2; qs++)
                pa[qs] = *(const bf16x8*)((const char*)&Pl[w][qs * 16 + l15][0] + (coff ^ fK));
#pragma unroll
            for (int is = 0; is < 8; is++) {
                bf16x8 vf = *(const bf16x8*)((const char*)&Vl[buf][is * 16 + l15][0] + (coff ^ fK));
                acc[0][is] = __builtin_amdgcn_mfma_f32_16x16x32_bf16(pa[0], vf, acc[0][is], 0, 0, 0);
                acc[1][is] = __builtin_amdgcn_mfma_f32_16x16x32_bf16(pa[1], vf, acc[1][is], 0, 0, 0);
            }
        }
        __syncthreads();
        buf ^= 1;
        mt += NSPLIT;
    }

#pragma unroll
    for (int qs = 0; qs < 2; qs++) {
        denom[qs] += __shfl_xor(denom[qs], 16);
        denom[qs] += __shfl_xor(denom[qs], 32);
    }

    float* op = Opart + ((size_t)(s * 4 + b)) * N * 128;
#pragma unroll
    for (int qs = 0; qs < 2; qs++)
#pragma unroll
        for (int is = 0; is < 8; is++)
#pragma unroll
            for (int r = 0; r < 4; r++) {
                const int n = q0w + qs * 16 + lhi * 4 + r;
                if (n < N) op[(size_t)n * 128 + is * 16 + l15] = acc[qs][is][r];
            }
    if (lhi == 0) {
#pragma unroll
        for (int qs = 0; qs < 2; qs++) {
            const int n = q0w + qs * 16 + l15;
            if (n < N) dpart[(size_t)(s * 4 + b) * N + n] = denom[qs];
        }
    }
}

// ---------------- fused combine + de-norm + up conv + residual ----------
// grid (98, 4), block 256 = 4 waves. Phase A: y tile (XOR-swizzled LDS) from
// Opart/dpart + glob stats. Phase B: MFMA GEMM + bias + maps residual.
__global__ __launch_bounds__(256) void conv_out_f(const float* __restrict__ Opart,
                                                  const float* __restrict__ dpart,
                                                  const float* __restrict__ st,
                                                  const short* __restrict__ wupb,
                                                  const float* __restrict__ bup,
                                                  const float* __restrict__ maps,
                                                  float* __restrict__ out)
{
    const int n0 = blockIdx.x * 32, b = blockIdx.y;
    const int t = threadIdx.x;

    __shared__ float denl[32];
    __shared__ __align__(16) short Yl[32][128];    // XOR-swizzled rows

    if (t < 32) {
        float d = 0.f;
#pragma unroll
        for (int s = 0; s < NSPLIT; s++) d += dpart[(size_t)(s * 4 + b) * NTOK + n0 + t];
        denl[t] = 1.0f / d;
    }
    __syncthreads();

#pragma unroll
    for (int g = 0; g < 2; g++) {
        const int e = t + g * 256;          // 0..511
        const int nl = e >> 4, icg = (e & 15) * 8;
        const float rdn = denl[nl];
        float sum[8] = {0.f, 0.f, 0.f, 0.f, 0.f, 0.f, 0.f, 0.f};
#pragma unroll
        for (int s = 0; s < NSPLIT; s++) {
            const size_t base = ((size_t)(s * 4 + b) * NTOK + n0 + nl) * 128 + icg;
            const f32x4 a = *(const f32x4*)(Opart + base);
            const f32x4 c = *(const f32x4*)(Opart + base + 4);
#pragma unroll
            for (int j = 0; j < 4; j++) { sum[j] += a[j]; sum[4 + j] += c[j]; }
        }
        const f32x4 mA = *(const f32x4*)(st + 128 + icg);
        const f32x4 mB = *(const f32x4*)(st + 128 + icg + 4);
        const f32x4 rA = *(const f32x4*)(st + 384 + icg);
        const f32x4 rB = *(const f32x4*)(st + 384 + icg + 4);
        s16x4 v0, v1;
#pragma unroll
        for (int j = 0; j < 4; j++) v0[j] = f2bf((sum[j] * rdn - mA[j]) * rA[j]);
#pragma unroll
        for (int j = 0; j < 4; j++) v1[j] = f2bf((sum[4 + j] * rdn - mB[j]) * rB[j]);
        char* ybase = (char*)&Yl[nl][0];
        const int sw = (nl & 7) << 4;
        *(s16x4*)(ybase + ((icg * 2) ^ sw)) = v0;
        *(s16x4*)(ybase + (((icg * 2) ^ sw) + 8)) = v1;
    }
    __syncthreads();

    const int wv = __builtin_amdgcn_readfirstlane(t >> 6);
    const int lane = t & 63;
    const int l15 = lane & 15, lhi = lane >> 4;
    const int c0 = wv * 128;
    const int fY = (l15 & 7) << 4;

    f32x4 acc[8][2];
#pragma unroll
    for (int g = 0; g < 8; g++)
#pragma unroll
        for (int j = 0; j < 2; j++) acc[g][j] = f32x4{0.f, 0.f, 0.f, 0.f};

#pragma unroll
    for (int ks = 0; ks < 4; ks++) {
        bf16x8 af[8], bv[2];
#pragma unroll
        for (int g = 0; g < 8; g++)
            af[g] = *(const bf16x8*)(wupb + (size_t)(c0 + g * 16 + l15) * 128 + ks * 32 + lhi * 8);
#pragma unroll
        for (int j = 0; j < 2; j++)
            bv[j] = *(const bf16x8*)((const char*)&Yl[j * 16 + l15][0] + ((ks * 64 + lhi * 16) ^ fY));
#pragma unroll
        for (int g = 0; g < 8; g++)
#pragma unroll
            for (int j = 0; j < 2; j++)
                acc[g][j] = __builtin_amdgcn_mfma_f32_16x16x32_bf16(af[g], bv[j], acc[g][j], 0, 0, 0);
    }
#pragma unroll
    for (int g = 0; g < 8; g++)
#pragma unroll
        for (int j = 0; j < 2; j++)
#pragma unroll
            for (int r = 0; r < 4; r++) {
                const int c = c0 + g * 16 + lhi * 4 + r;
                const int n = n0 + j * 16 + l15;
                const size_t o = ((size_t)b * 512 + c) * NTOK + n;
                out[o] = acc[g][j][r] + bup[c] + maps[o];
            }
}

extern "C" void kernel_launch(void* const* d_in, const int* in_sizes, int n_in,
                              void* d_out, int out_size, void* d_ws, size_t ws_size,
                              hipStream_t stream)
{
    const float* maps    = (const float*)d_in[0];
    const float* w_theta = (const float*)d_in[1];
    const float* w_glob  = (const float*)d_in[5];
    const float* w_up    = (const float*)d_in[7];
    const float* b_up    = (const float*)d_in[8];
    float* out = (float*)d_out;

    // workspace (~33.5 MB)
    short* Tt    = (short*)d_ws;               // NELEM (theta pre-norm, [b][n][ic])
    short* Gpre  = Tt + NELEM;                 // NELEM (glob pre-norm, [b][ic][n])
    short* Wb    = Gpre + NELEM;               // 131072 shorts
    short* wupb  = Wb + 131072;                // 65536 shorts
    float* st    = (float*)(wupb + 65536);     // 512 f32
    float* psum  = st + 512;                   // 256*392 f32
    float* psq   = psum + 100352;              // 256*392 f32
    float* dpart = psq + 100352;               // NSPLIT*4*3136 f32
    float* Opart = dpart + 50176;              // NSPLIT*4*3136*128 f32 = 25.7 MB

    prep_w    <<<768,             256, 0, stream>>>(w_theta, w_glob, w_up, Wb, wupb);
    conv_in_f <<<dim3(98, 4),     256, 0, stream>>>(maps, Wb, Tt, Gpre, psum, psq);
    stats_fin <<<256,             64,  0, stream>>>(psum, psq, st);
    attn_k    <<<dim3(25, 4, NSPLIT), 256, 0, stream>>>(Tt, Gpre, st, Opart, dpart);
    conv_out_f<<<dim3(98, 4),     256, 0, stream>>>(Opart, dpart, st, wupb, b_up, maps, out);
}

// Round 7
// 87.532 us; speedup vs baseline: 6.1574x; 1.0496x over previous
//
#include <hip/hip_runtime.h>
#include <hip/hip_bf16.h>

// B=4, C=512, IC=128, N=3136
// prep_w     : bf16-ize weights  Wb[256][512] (theta|glob stacked), wupb[512][128]
// conv_in_f  : fused MFMA GEMM from maps (f32) with in-LDS bf16 transpose staging.
//              Writes Tt bf16 [b][n][ic] (theta pre-norm, transposed) and
//              Gpre bf16 [b][ic][n] (glob pre-norm) + per-block channel partials.
// stats_fin  : reduce partials -> st[512] (means, rstds)
// attn_k     : KV-split (S=4) flash attention, 32x32x16 MFMA, BN folded:
//                K = raw Tt (softmax row-constant drops), Q = (t-mu)*rho^2 at load,
//                V = raw Gpre (BN applied post-hoc in conv_out_f).
//              Swapped QK^T (mfma(K,Q)): lane holds P columns for q=lane&31;
//              P stays IN REGISTER: v_perm_b32 pack + v_permlane32_swap
//              redistribution -> PV A-frags directly (no P LDS at all).
//              K/V LDS-staged (global_load_lds 16B, XOR-swizzled, dbuf).
//              Partials: Opart[s][b][n][ic] f32 (in d_ws) + dpart.
// conv_out_f : fused combine + de-norm + MFMA GEMM + bias + residual -> out.

typedef __attribute__((ext_vector_type(8))) short bf16x8;
typedef __attribute__((ext_vector_type(4))) float f32x4;
typedef __attribute__((ext_vector_type(16))) float f32x16;
typedef __attribute__((ext_vector_type(4))) short s16x4;

#define NTOK 3136
#define NELEM 1605632   // 4*128*3136
#define NSPLIT 4

__device__ inline float bf2f(short u) {
    union { unsigned int i; float f; } v;
    v.i = ((unsigned int)(unsigned short)u) << 16;
    return v.f;
}
__device__ inline short f2bf(float x) {
    union { float f; unsigned int i; } v;
    v.f = x;
    unsigned int r = v.i + 0x7FFFu + ((v.i >> 16) & 1u); // RNE
    return (short)(r >> 16);
}
// pack two f32 -> u32 of 2 bf16 (truncation) in ONE v_perm_b32
__device__ inline unsigned pk2(float lo, float hi) {
    union { float f; unsigned u; } a, b;
    a.f = lo; b.f = hi;
    return __builtin_amdgcn_perm(b.u, a.u, 0x07060302u);
}
// v_permlane32_swap_b32: a.hi-lanes <-> b.lo-lanes
__device__ inline void pl32swap(unsigned &a, unsigned &b) {
    asm("v_permlane32_swap_b32 %0, %1" : "+v"(a), "+v"(b));
}
__device__ inline void glds16(const void* g, void* l) {
    __builtin_amdgcn_global_load_lds((const __attribute__((address_space(1))) void*)g,
                                     (__attribute__((address_space(3))) void*)l, 16, 0, 0);
}

// ---------------- prep: weights -> bf16 ---------------------------------
__global__ __launch_bounds__(256) void prep_w(const float* __restrict__ wt,
                                              const float* __restrict__ wg,
                                              const float* __restrict__ wup,
                                              short* __restrict__ Wb,
                                              short* __restrict__ wupb)
{
    const int i = blockIdx.x * 256 + threadIdx.x;
    if (i < 131072) {
        const int r = i >> 9;
        const int c = i & 511;
        const float w = (r < 128) ? wt[(size_t)r * 512 + c] : wg[(size_t)(r - 128) * 512 + c];
        Wb[i] = f2bf(w);
    } else {
        const int j = i - 131072;
        wupb[j] = f2bf(wup[j]);
    }
}

// ---------------- fused input conv --------------------------------------
// grid (98, 4) = (32-n tile, b), block 256 = 4 waves.
__global__ __launch_bounds__(256) void conv_in_f(const float* __restrict__ maps,
                                                 const short* __restrict__ Wb,
                                                 short* __restrict__ Tt,
                                                 short* __restrict__ Gpre,
                                                 float* __restrict__ psum,
                                                 float* __restrict__ psq)
{
    const int nt = blockIdx.x, b = blockIdx.y;
    const int n0 = nt * 32;
    const int t = threadIdx.x;
    const int w = __builtin_amdgcn_readfirstlane(t >> 6);
    const int lane = t & 63;
    const int l15 = lane & 15, lhi = lane >> 4;

    __shared__ short Bt[32][136];   // [n][c-chunk], +8 pad

    const float* mp = maps + (size_t)b * 512 * NTOK + n0;
    const int cl = t >> 3;          // 0..31
    const int f4 = t & 7;           // float4 index along n

    f32x4 acc[4][2];
#pragma unroll
    for (int g = 0; g < 4; g++)
#pragma unroll
        for (int j = 0; j < 2; j++) acc[g][j] = f32x4{0.f, 0.f, 0.f, 0.f};

    f32x4 rg[4];
#pragma unroll
    for (int p = 0; p < 4; p++)
        rg[p] = *(const f32x4*)(mp + (size_t)(p * 32 + cl) * NTOK + f4 * 4);

    for (int kc = 0; kc < 4; kc++) {
        __syncthreads();
#pragma unroll
        for (int p = 0; p < 4; p++) {
            const int cc = p * 32 + cl;
#pragma unroll
            for (int i = 0; i < 4; i++) Bt[f4 * 4 + i][cc] = f2bf(rg[p][i]);
        }
        if (kc < 3) {
#pragma unroll
            for (int p = 0; p < 4; p++)
                rg[p] = *(const f32x4*)(mp + (size_t)((kc + 1) * 128 + p * 32 + cl) * NTOK + f4 * 4);
        }
        __syncthreads();
#pragma unroll
        for (int ks = 0; ks < 4; ks++) {
            bf16x8 af[4], bv[2];
#pragma unroll
            for (int g = 0; g < 4; g++)
                af[g] = *(const bf16x8*)(Wb + (size_t)(w * 64 + g * 16 + l15) * 512 + kc * 128 + ks * 32 + lhi * 8);
#pragma unroll
            for (int j = 0; j < 2; j++)
                bv[j] = *(const bf16x8*)(&Bt[j * 16 + l15][ks * 32 + lhi * 8]);
#pragma unroll
            for (int g = 0; g < 4; g++)
#pragma unroll
                for (int j = 0; j < 2; j++)
                    acc[g][j] = __builtin_amdgcn_mfma_f32_16x16x32_bf16(af[g], bv[j], acc[g][j], 0, 0, 0);
        }
    }

    // ---- outputs. D layout: col(l15)=n_local, row(lhi*4+r)=ch_local ----
    if (w < 2) {
#pragma unroll
        for (int g = 0; g < 4; g++)
#pragma unroll
            for (int j = 0; j < 2; j++) {
                s16x4 v;
#pragma unroll
                for (int r = 0; r < 4; r++) v[r] = f2bf(acc[g][j][r]);
                *(s16x4*)(Tt + ((size_t)b * NTOK + n0 + j * 16 + l15) * 128 + w * 64 + g * 16 + lhi * 4) = v;
            }
    } else {
#pragma unroll
        for (int g = 0; g < 4; g++)
#pragma unroll
            for (int j = 0; j < 2; j++)
#pragma unroll
                for (int r = 0; r < 4; r++) {
                    const int icg = (w - 2) * 64 + g * 16 + lhi * 4 + r;
                    Gpre[((size_t)b * 128 + icg) * NTOK + n0 + j * 16 + l15] = f2bf(acc[g][j][r]);
                }
    }
#pragma unroll
    for (int g = 0; g < 4; g++)
#pragma unroll
        for (int r = 0; r < 4; r++) {
            float s = acc[g][0][r] + acc[g][1][r];
            float q = acc[g][0][r] * acc[g][0][r] + acc[g][1][r] * acc[g][1][r];
#pragma unroll
            for (int off = 1; off < 16; off <<= 1) {
                s += __shfl_xor(s, off);
                q += __shfl_xor(q, off);
            }
            if (l15 == 0) {
                const int ch = w * 64 + g * 16 + lhi * 4 + r;  // 0-127 theta, 128-255 glob
                psum[(size_t)ch * 392 + b * 98 + nt] = s;
                psq [(size_t)ch * 392 + b * 98 + nt] = q;
            }
        }
}

// ---------------- finalize stats ----------------------------------------
__global__ __launch_bounds__(64) void stats_fin(const float* __restrict__ psum,
                                                const float* __restrict__ psq,
                                                float* __restrict__ st)
{
    const int ch = blockIdx.x;
    const int lane = threadIdx.x;
    float s = 0.f, q = 0.f;
    for (int i = lane; i < 392; i += 64) {
        s += psum[(size_t)ch * 392 + i];
        q += psq [(size_t)ch * 392 + i];
    }
#pragma unroll
    for (int off = 32; off; off >>= 1) { s += __shfl_xor(s, off); q += __shfl_xor(q, off); }
    if (lane == 0) {
        const float mean = s / 12544.f;
        const float var = q / 12544.f - mean * mean;
        st[ch] = mean;
        st[256 + ch] = rsqrtf(var + 1e-5f);
    }
}

// ---------------- attention: 32x32 MFMA, in-register P ------------------
// grid (25, B=4, S=4), block 256 = 4 waves; wave owns 32 q-rows.
// QK^T swapped: sv = mfma(K, Q) -> col=q=lane&31, row=m=(r&3)+8(r>>2)+4(lane>>5).
// P pack: pk2 pairs + permlane32_swap -> PV A-frags in-register.
__global__ __launch_bounds__(256, 2) void attn_k(const short* __restrict__ Tt,
                                                 const short* __restrict__ Gpre,
                                                 const float* __restrict__ st,
                                                 float* __restrict__ Opart,
                                                 float* __restrict__ dpart)
{
    constexpr int N = NTOK;
    const int b = blockIdx.y, s = blockIdx.z;
    const int w = __builtin_amdgcn_readfirstlane(threadIdx.x >> 6);
    const int lane = threadIdx.x & 63;
    const int l31 = lane & 31, hi = lane >> 5;
    const int q0w = blockIdx.x * 128 + w * 32;

    __shared__ __align__(16) short Kl[2][64][128];  // 32 KB: K tile [m][ic]
    __shared__ __align__(16) short Vl[2][128][64];  // 32 KB: V tile [ic][m]

    const short* tb = Tt + (size_t)b * N * 128;
    const short* gb = Gpre + (size_t)b * 128 * N;

    // Q B-frags (col=q=l31, k(ic)=ks*16+hi*8+j), BN folded: q=(t-mu)*rho^2
    bf16x8 qf[8];
    {
        int row = q0w + l31; row = row < N ? row : N - 1;
        const short* qp = tb + (size_t)row * 128;
#pragma unroll
        for (int ks = 0; ks < 8; ks++) {
            const int c0 = ks * 16 + hi * 8;
            const bf16x8 v = *(const bf16x8*)(qp + c0);
            const f32x4 mA = *(const f32x4*)(st + c0);
            const f32x4 mB = *(const f32x4*)(st + c0 + 4);
            const f32x4 rA = *(const f32x4*)(st + 256 + c0);
            const f32x4 rB = *(const f32x4*)(st + 256 + c0 + 4);
            bf16x8 q;
#pragma unroll
            for (int j = 0; j < 4; j++) q[j] = f2bf((bf2f(v[j]) - mA[j]) * (rA[j] * rA[j]));
#pragma unroll
            for (int j = 0; j < 4; j++) q[4 + j] = f2bf((bf2f(v[4 + j]) - mB[j]) * (rB[j] * rB[j]));
            qf[ks] = q;
        }
    }

    f32x16 accv[4];
#pragma unroll
    for (int it = 0; it < 4; it++)
#pragma unroll
        for (int r = 0; r < 16; r++) accv[it][r] = 0.f;
    float denom = 0.f;
    const float inv_n = 1.0f / (float)N;

    auto STAGE = [&](int bufi, int m0) {
#pragma unroll
        for (int i = 0; i < 4; i++) {
            const int rb = w * 16 + i * 4;
            const int krow = rb + (lane >> 4);
            const int ls = (lane & 15) ^ (krow & 7);      // pre-swizzled source line
            glds16(tb + (size_t)(m0 + krow) * 128 + ls * 8, (void*)&Kl[bufi][rb][0]);
        }
#pragma unroll
        for (int i = 0; i < 4; i++) {
            const int rb = w * 32 + i * 8;
            const int vrow = rb + (lane >> 3);
            const int ls = (lane & 7) ^ (vrow & 7);
            glds16(gb + (size_t)vrow * N + m0 + ls * 8, (void*)&Vl[bufi][rb][0]);
        }
    };

    const int nt = (49 - s + NSPLIT - 1) / NSPLIT;
    int mt = s;
    STAGE(0, mt * 64);
    __syncthreads();
    int buf = 0;

    const int fr = (l31 & 7) << 4;

    // exp + pack one 32-m half -> two PV A-frags (m 16-blocks)
    auto mkpa = [&](const f32x16 &sv, bf16x8 *dst) {
        float e[16];
#pragma unroll
        for (int r = 0; r < 16; r++) { e[r] = __expf(sv[r] * inv_n); denom += e[r]; }
        unsigned c0 = pk2(e[0], e[1]),  c1 = pk2(e[2], e[3]);
        unsigned c2 = pk2(e[4], e[5]),  c3 = pk2(e[6], e[7]);
        unsigned c4 = pk2(e[8], e[9]),  c5 = pk2(e[10], e[11]);
        unsigned c6 = pk2(e[12], e[13]), c7 = pk2(e[14], e[15]);
        pl32swap(c0, c2); pl32swap(c1, c3); pl32swap(c4, c6); pl32swap(c5, c7);
        union U { unsigned u[4]; bf16x8 v; } f0, f1;
        f0.u[0] = c0; f0.u[1] = c1; f0.u[2] = c2; f0.u[3] = c3;
        f1.u[0] = c4; f1.u[1] = c5; f1.u[2] = c6; f1.u[3] = c7;
        dst[0] = f0.v; dst[1] = f1.v;
    };

    for (int t = 0; t < nt; ++t) {
        if (t + 1 < nt) STAGE(buf ^ 1, (mt + NSPLIT) * 64);

        // --- QK^T: A = K rows (m), B = Q; 8 k-steps over 128 ic ---
        f32x16 sv0, sv1;
#pragma unroll
        for (int r = 0; r < 16; r++) { sv0[r] = 0.f; sv1[r] = 0.f; }
#pragma unroll
        for (int ks = 0; ks < 8; ks++) {
            const int co = (ks * 32 + hi * 16) ^ fr;
            bf16x8 kf0 = *(const bf16x8*)((const char*)&Kl[buf][l31][0] + co);
            bf16x8 kf1 = *(const bf16x8*)((const char*)&Kl[buf][32 + l31][0] + co);
            sv0 = __builtin_amdgcn_mfma_f32_32x32x16_bf16(kf0, qf[ks], sv0, 0, 0, 0);
            sv1 = __builtin_amdgcn_mfma_f32_32x32x16_bf16(kf1, qf[ks], sv1, 0, 0, 0);
        }

        // --- exp -> in-register P A-frags (no LDS) ---
        bf16x8 pa[4];
        mkpa(sv0, &pa[0]);   // m 0..31  -> k-steps 0,1
        mkpa(sv1, &pa[2]);   // m 32..63 -> k-steps 2,3

        // --- PV: A = P (rows q), B = V (cols ic), k = m ---
#pragma unroll
        for (int kp = 0; kp < 4; kp++) {
            const int cv = kp * 32 + hi * 16;
#pragma unroll
            for (int it = 0; it < 4; it++) {
                const int row = it * 32 + l31;
                bf16x8 vf = *(const bf16x8*)((const char*)&Vl[buf][row][0] + (cv ^ fr));
                accv[it] = __builtin_amdgcn_mfma_f32_32x32x16_bf16(pa[kp], vf, accv[it], 0, 0, 0);
            }
        }
        __syncthreads();
        buf ^= 1;
        mt += NSPLIT;
    }

    // denom: lane holds sum over its m-half for q=l31; combine halves
    denom += __shfl_xor(denom, 32);

    float* op = Opart + ((size_t)(s * 4 + b)) * N * 128;
    // accv layout: col(l31)=ic_local, row=(r&3)+8(r>>2)+4hi = q_local
#pragma unroll
    for (int it = 0; it < 4; it++)
#pragma unroll
        for (int r = 0; r < 16; r++) {
            const int n = q0w + (r & 3) + 8 * (r >> 2) + 4 * hi;
            if (n < N) op[(size_t)n * 128 + it * 32 + l31] = accv[it][r];
        }
    if (lane < 32) {
        const int n = q0w + l31;
        if (n < N) dpart[(size_t)(s * 4 + b) * N + n] = denom;
    }
}

// ---------------- fused combine + de-norm + up conv + residual ----------
// grid (98, 4), block 256 = 4 waves.
__global__ __launch_bounds__(256) void conv_out_f(const float* __restrict__ Opart,
                                                  const float* __restrict__ dpart,
                                                  const float* __restrict__ st,
                                                  const short* __restrict__ wupb,
                                                  const float* __restrict__ bup,
                                                  const float* __restrict__ maps,
                                                  float* __restrict__ out)
{
    const int n0 = blockIdx.x * 32, b = blockIdx.y;
    const int t = threadIdx.x;

    __shared__ float denl[32];
    __shared__ __align__(16) short Yl[32][128];    // XOR-swizzled rows

    if (t < 32) {
        float d = 0.f;
#pragma unroll
        for (int s = 0; s < NSPLIT; s++) d += dpart[(size_t)(s * 4 + b) * NTOK + n0 + t];
        denl[t] = 1.0f / d;
    }
    __syncthreads();

#pragma unroll
    for (int g = 0; g < 2; g++) {
        const int e = t + g * 256;          // 0..511
        const int nl = e >> 4, icg = (e & 15) * 8;
        const float rdn = denl[nl];
        float sum[8] = {0.f, 0.f, 0.f, 0.f, 0.f, 0.f, 0.f, 0.f};
#pragma unroll
        for (int s = 0; s < NSPLIT; s++) {
            const size_t base = ((size_t)(s * 4 + b) * NTOK + n0 + nl) * 128 + icg;
            const f32x4 a = *(const f32x4*)(Opart + base);
            const f32x4 c = *(const f32x4*)(Opart + base + 4);
#pragma unroll
            for (int j = 0; j < 4; j++) { sum[j] += a[j]; sum[4 + j] += c[j]; }
        }
        const f32x4 mA = *(const f32x4*)(st + 128 + icg);
        const f32x4 mB = *(const f32x4*)(st + 128 + icg + 4);
        const f32x4 rA = *(const f32x4*)(st + 384 + icg);
        const f32x4 rB = *(const f32x4*)(st + 384 + icg + 4);
        s16x4 v0, v1;
#pragma unroll
        for (int j = 0; j < 4; j++) v0[j] = f2bf((sum[j] * rdn - mA[j]) * rA[j]);
#pragma unroll
        for (int j = 0; j < 4; j++) v1[j] = f2bf((sum[4 + j] * rdn - mB[j]) * rB[j]);
        char* ybase = (char*)&Yl[nl][0];
        const int sw = (nl & 7) << 4;
        *(s16x4*)(ybase + ((icg * 2) ^ sw)) = v0;
        *(s16x4*)(ybase + (((icg * 2) ^ sw) + 8)) = v1;
    }
    __syncthreads();

    const int wv = __builtin_amdgcn_readfirstlane(t >> 6);
    const int lane = t & 63;
    const int l15 = lane & 15, lhi = lane >> 4;
    const int c0 = wv * 128;
    const int fY = (l15 & 7) << 4;

    f32x4 acc[8][2];
#pragma unroll
    for (int g = 0; g < 8; g++)
#pragma unroll
        for (int j = 0; j < 2; j++) acc[g][j] = f32x4{0.f, 0.f, 0.f, 0.f};

#pragma unroll
    for (int ks = 0; ks < 4; ks++) {
        bf16x8 af[8], bv[2];
#pragma unroll
        for (int g = 0; g < 8; g++)
            af[g] = *(const bf16x8*)(wupb + (size_t)(c0 + g * 16 + l15) * 128 + ks * 32 + lhi * 8);
#pragma unroll
        for (int j = 0; j < 2; j++)
            bv[j] = *(const bf16x8*)((const char*)&Yl[j * 16 + l15][0] + ((ks * 64 + lhi * 16) ^ fY));
#pragma unroll
        for (int g = 0; g < 8; g++)
#pragma unroll
            for (int j = 0; j < 2; j++)
                acc[g][j] = __builtin_amdgcn_mfma_f32_16x16x32_bf16(af[g], bv[j], acc[g][j], 0, 0, 0);
    }
#pragma unroll
    for (int g = 0; g < 8; g++)
#pragma unroll
        for (int j = 0; j < 2; j++)
#pragma unroll
            for (int r = 0; r < 4; r++) {
                const int c = c0 + g * 16 + lhi * 4 + r;
                const int n = n0 + j * 16 + l15;
                const size_t o = ((size_t)b * 512 + c) * NTOK + n;
                out[o] = acc[g][j][r] + bup[c] + maps[o];
            }
}

extern "C" void kernel_launch(void* const* d_in, const int* in_sizes, int n_in,
                              void* d_out, int out_size, void* d_ws, size_t ws_size,
                              hipStream_t stream)
{
    const float* maps    = (const float*)d_in[0];
    const float* w_theta = (const float*)d_in[1];
    const float* w_glob  = (const float*)d_in[5];
    const float* w_up    = (const float*)d_in[7];
    const float* b_up    = (const float*)d_in[8];
    float* out = (float*)d_out;

    // workspace (~33.5 MB)
    short* Tt    = (short*)d_ws;               // NELEM (theta pre-norm, [b][n][ic])
    short* Gpre  = Tt + NELEM;                 // NELEM (glob pre-norm, [b][ic][n])
    short* Wb    = Gpre + NELEM;               // 131072 shorts
    short* wupb  = Wb + 131072;                // 65536 shorts
    float* st    = (float*)(wupb + 65536);     // 512 f32
    float* psum  = st + 512;                   // 256*392 f32
    float* psq   = psum + 100352;              // 256*392 f32
    float* dpart = psq + 100352;               // NSPLIT*4*3136 f32
    float* Opart = dpart + 50176;              // NSPLIT*4*3136*128 f32 = 25.7 MB

    prep_w    <<<768,             256, 0, stream>>>(w_theta, w_glob, w_up, Wb, wupb);
    conv_in_f <<<dim3(98, 4),     256, 0, stream>>>(maps, Wb, Tt, Gpre, psum, psq);
    stats_fin <<<256,             64,  0, stream>>>(psum, psq, st);
    attn_k    <<<dim3(25, 4, NSPLIT), 256, 0, stream>>>(Tt, Gpre, st, Opart, dpart);
    conv_out_f<<<dim3(98, 4),     256, 0, stream>>>(Opart, dpart, st, wupb, b_up, maps, out);
}